// Round 13
// baseline (617.273 us; speedup 1.0000x reference)
//
#include <hip/hip_runtime.h>
#include <hip/hip_bf16.h>

// ---------------- problem constants ----------------
#define SQ   64        // seq len
#define NN   1000      // nodes per graph
#define NT   64000     // total nodes
#define EE   128       // emb dim
#define EG   512000    // graph edges (no self loops)
#define ET   576000    // edges + self loops

// ---------------- workspace layout (bytes) ----------------
// common / fallback region (<71 MB)
#define WS_XA      0ull          // 32,768,000  float[NT*128]  x ping (fallback mu)
#define WS_PHI     0ull          // 16,384,000  ushort hi-plane (packed A, aliases XA)
#define WS_PLO     16500000ull   // 16,384,000  ushort lo-plane (packed A, aliases XA)
#define WS_XB      33000000ull   // 32,768,000  float[NT*128]  x pong (xl / la)
#define WS_ROWPTR  66000000ull   // 256,004     int[NT+1]
#define WS_CURSOR  66300000ull   // 256,000     int[NT]
#define WS_SRCS    66600000ull   // 2,304,000   int[ET]  (src node id, dst-grouped)
#define WS_INCL    69000000ull   // 256,000     int[NT]
#define WS_BSUM    69300000ull   // 1,024       int[250]
#define WS_MODE    69304096ull   // 4           int
#define WS_WQA     70000000ull   // 262,144     float4[64*256]  (fallback LSTM)
#define WS_WQB     70262144ull   // 262,144     float4[64*256]  (fallback LSTM)
#define WS_LOGIT2  70700000ull   // 256,000     float[NT]
// big-ws region: xC aliases xB + CSR (disjoint lifetimes)
#define WS2_XC     33000000ull   // 131,072,000 float[NT*512]  gate preacts (row-major)
#define WS2_BFRAG  164100000ull  // 131,072     ushort bf16 Whh B-fragments (LSTM)
#define WS2_GHI    164300000ull  // 311,296     ushort GEMM W fragments (hi)
#define WS2_GLO    164650000ull  // 311,296     ushort GEMM W fragments (lo)
#define WS2_B512   165000000ull  // 2,048       float[512]     bih+bhh
#define WS2_MODE   165010000ull  // 4
#define WS2_LOGIT2 165100000ull  // 256,000
#define WS2_NEED   165360000ull
// GEMM fragment sub-offsets (ushort elements within GHI/GLO)
#define G_W1    0        // 64x128  -> 8192
#define G_WL    8192     // 4 x 128x128 -> 16384 each
#define G_PROJ  73728    // 128x512 -> 65536
#define G_W7    139264   // 128x128 -> 16384
// packed-A plane: 1000 tiles x 8192 ushorts (K=128 fragment order)
#define PTILE   8192

typedef __attribute__((ext_vector_type(8))) short short8;   // 8 bf16 (4 VGPRs)
typedef __attribute__((ext_vector_type(4))) float f32x4;

// ---------------- helpers ----------------
__device__ __forceinline__ float rdlane(float v, int l) {
    return __int_as_float(__builtin_amdgcn_readlane(__float_as_int(v), l));
}
__device__ __forceinline__ float sigm(float x) { return 1.0f / (1.0f + __expf(-x)); }
__device__ __forceinline__ float tanh_f(float x) {
    x = fminf(fmaxf(x, -30.0f), 30.0f);
    float e = __expf(2.0f * x);
    return (e - 1.0f) / (e + 1.0f);
}
__device__ __forceinline__ float tanh2(float x) {   // 2*sigmoid(2x)-1, inf-safe
    return 2.0f / (1.0f + __expf(-2.0f * x)) - 1.0f;
}
__device__ __forceinline__ ushort f2bf(float x) {   // round-to-nearest-even bf16
    unsigned u = __float_as_uint(x);
    unsigned r = (u + 0x7FFFu + ((u >> 16) & 1u)) >> 16;
    return (ushort)r;
}
__device__ __forceinline__ float bf2f(ushort h) {
    return __uint_as_float(((unsigned)h) << 16);
}

// ---------------- reachable dtype detection ----------------
__global__ void detect_mode_k(const unsigned char* __restrict__ p, int* __restrict__ mode) {
    __shared__ int f0, f3;
    const int t = threadIdx.x;
    if (t == 0) { f0 = 0; f3 = 0; }
    __syncthreads();
    int l0 = 0, l3 = 0;
    for (int i = t; i < 16000; i += 1024) {
        if (p[4 * i])     l0 = 1;
        if (p[4 * i + 3]) l3 = 1;
    }
    if (l0) atomicOr(&f0, 1);
    if (l3) atomicOr(&f3, 1);
    __syncthreads();
    if (t == 0) {
        int m;
        if (f0 && f3)      m = 1;  // bool bytes
        else if (f0)       m = 0;  // int32
        else               m = 2;  // float32
        *mode = m;
    }
}

// ---------------- CSR construction (dst-grouped src list; built once) ----------------
__global__ void zero_ints_k(int* __restrict__ p, int n) {
    int i = blockIdx.x * 256 + threadIdx.x;
    if (i < n) p[i] = 0;
}
__global__ void hist_k(const int* __restrict__ ei, int* __restrict__ deg) {
    int e = blockIdx.x * 256 + threadIdx.x;
    if (e < ET) {
        int d = (e < EG) ? ei[EG + e] : (e - EG);
        atomicAdd(deg + d, 1);
    }
}
__global__ void scan1_k(const int* __restrict__ deg, int* __restrict__ incl, int* __restrict__ bsum) {
    __shared__ int sh[256];
    const int t = threadIdx.x;
    const int i = blockIdx.x * 256 + t;
    sh[t] = deg[i];
    __syncthreads();
    for (int o = 1; o < 256; o <<= 1) {
        int add = (t >= o) ? sh[t - o] : 0;
        __syncthreads();
        sh[t] += add;
        __syncthreads();
    }
    incl[i] = sh[t];
    if (t == 255) bsum[blockIdx.x] = sh[255];
}
// scan3 with INLINE block-offset reduction (absorbs the old scan2's single-block
// launch bubble). rowptr bitwise identical to the scan2+scan3 pair.
__global__ void scan3_k(const int* __restrict__ incl, const int* __restrict__ bsum,
                        int* __restrict__ rowptr, int* __restrict__ cursor_deg) {
    __shared__ int sh[256];
    const int t = threadIdx.x;
    const int i = blockIdx.x * 256 + t;
    sh[t] = (t < blockIdx.x) ? bsum[t] : 0;   // blockIdx.x <= 249 < 256
    __syncthreads();
    for (int o = 128; o; o >>= 1) {
        if (t < o) sh[t] += sh[t + o];
        __syncthreads();
    }
    const int boff = sh[0];
    int total = incl[i] + boff;
    int excl  = total - cursor_deg[i];
    rowptr[i] = excl;
    cursor_deg[i] = excl;                 // becomes fill cursor
    if (i == NT - 1) rowptr[NT] = total;
}
__global__ void fill_k(const int* __restrict__ ei, int* __restrict__ cursor, int* __restrict__ srcs) {
    int e = blockIdx.x * 256 + threadIdx.x;
    if (e < ET) {
        int s_, d_;
        if (e < EG) { s_ = ei[e]; d_ = ei[EG + e]; }
        else        { s_ = e - EG; d_ = s_; }
        int p = atomicAdd(cursor + d_, 1);
        srcs[p] = s_;
    }
}

// ---------------- fused weight-prep (big-ws): bfrag + bias512 + 6 gfrags ----------------
__device__ __forceinline__ void gfrag_dev(const float* __restrict__ src, const int ks,
                                          const int ns, const int K,
                                          ushort* __restrict__ dhi, ushort* __restrict__ dlo,
                                          const int total, const int id) {
    if (id < total) {
        int j = id & 7, lane = (id >> 3) & 63;
        int f = id >> 9;
        int KT = K >> 5;
        int nt = f / KT, kt = f - nt * KT;
        int n = nt * 16 + (lane & 15);
        int k = kt * 32 + ((lane >> 4) << 3) + j;
        float v = src[(size_t)k * ks + (size_t)n * ns];
        ushort h = f2bf(v);
        dhi[id] = h;
        dlo[id] = f2bf(v - bf2f(h));
    }
}
__global__ void build_all_k(const float* __restrict__ Whh, const float* __restrict__ bih,
                            const float* __restrict__ bhh, const float* __restrict__ W1,
                            const float* __restrict__ Wl, const float* __restrict__ Wih,
                            const float* __restrict__ W7, ushort* __restrict__ Bfrag,
                            float* __restrict__ b512, ushort* __restrict__ ghi,
                            ushort* __restrict__ glo) {
    const int b = blockIdx.x, t = threadIdx.x;
    if (b < 256) {                       // Whh B-fragments (LSTM), 65536 ids
        int id = b * 256 + t;
        int j = id & 7, lane = (id >> 3) & 63, kt = (id >> 9) & 3, tile = id >> 11;
        int gate = tile * 16 + (lane & 15);
        int k = kt * 32 + ((lane >> 4) << 3) + j;
        Bfrag[id] = f2bf(Whh[(size_t)gate * 128 + k]);
    } else if (b < 258) {                // bias512
        int i = (b - 256) * 256 + t;
        if (i < 512) b512[i] = bih[i] + bhh[i];
    } else if (b < 290) {                // W1: 64x128
        gfrag_dev(W1, 128, 1, 64, ghi + G_W1, glo + G_W1, 8192, (b - 258) * 256 + t);
    } else if (b < 546) {                // 4x Wl: 128x128 each, 64 blocks apiece
        int bb = b - 290;
        int i = bb >> 6;
        gfrag_dev(Wl + (size_t)i * 16384, 128, 1, 128,
                  ghi + G_WL + i * 16384, glo + G_WL + i * 16384, 16384, (bb & 63) * 256 + t);
    } else if (b < 802) {                // Wih: 128x512 (transposed access)
        gfrag_dev(Wih, 1, 128, 128, ghi + G_PROJ, glo + G_PROJ, 65536, (b - 546) * 256 + t);
    } else {                             // W7: 128x128
        gfrag_dev(W7, 128, 1, 128, ghi + G_W7, glo + G_W7, 16384, (b - 802) * 256 + t);
    }
}

// ---------------- MFMA GEMM (staged-A): out = x @ W + bias, split bf16 hi/lo ----------------
// Used where A is fp32 in memory (layer-1 gemm from nfm).
template <int KT>
__global__ __launch_bounds__(256) void gemm_mf(
    const float* __restrict__ x, const ushort* __restrict__ bhi,
    const ushort* __restrict__ blo, const float* __restrict__ bias,
    float* __restrict__ out, const int ldout)
{
    constexpr int K = KT * 32;
    __shared__ __align__(16) ushort ahi_s[KT * 4 * 64 * 8];
    __shared__ __align__(16) ushort alo_s[KT * 4 * 64 * 8];
    const int t = threadIdx.x;
    const int w = t >> 6, lane = t & 63;
    const int quad = lane >> 4, col = lane & 15;
    const int row0 = blockIdx.x * 64;
    const int col0 = blockIdx.y * 128;

    {
        const int r  = t >> 2;            // row 0..63
        const int kc = (t & 3) * (K / 4); // channel quarter
        const int rw = r >> 4, rcol = r & 15;
        const float* xr = x + (size_t)(row0 + r) * K + kc;
#pragma unroll
        for (int k = 0; k < K / 4; k += 4) {
            const int ch = kc + k;
            const int idx = (((ch >> 5) * 4 + rw) * 64 + ((ch >> 3) & 3) * 16 + rcol) * 8
                            + (ch & 7);
            float4 v = *(const float4*)(xr + k);
            ushort h0_ = f2bf(v.x), h1_ = f2bf(v.y), h2_ = f2bf(v.z), h3_ = f2bf(v.w);
            ushort l0_ = f2bf(v.x - bf2f(h0_)), l1_ = f2bf(v.y - bf2f(h1_));
            ushort l2_ = f2bf(v.z - bf2f(h2_)), l3_ = f2bf(v.w - bf2f(h3_));
            *(uint2*)(ahi_s + idx) = make_uint2((uint)h0_ | ((uint)h1_ << 16),
                                                (uint)h2_ | ((uint)h3_ << 16));
            *(uint2*)(alo_s + idx) = make_uint2((uint)l0_ | ((uint)l1_ << 16),
                                                (uint)l2_ | ((uint)l3_ << 16));
        }
    }
    __syncthreads();

    short8 ah[KT], al[KT];
#pragma unroll
    for (int kt = 0; kt < KT; kt++) {
        const int off = ((kt * 4 + w) * 64 + lane) * 8;
        ah[kt] = *(const short8*)(ahi_s + off);
        al[kt] = *(const short8*)(alo_s + off);
    }

    f32x4 acc[8];
#pragma unroll
    for (int q = 0; q < 8; q++) acc[q] = (f32x4){0.f, 0.f, 0.f, 0.f};

#pragma unroll
    for (int q = 0; q < 8; q++) {
#pragma unroll
        for (int kt = 0; kt < KT; kt++) {
            const int f = ((((col0 >> 4) + q) * KT + kt) * 64 + lane) * 8;
            short8 bh = *(const short8*)(bhi + f);
            short8 bl = *(const short8*)(blo + f);
            acc[q] = __builtin_amdgcn_mfma_f32_16x16x32_bf16(ah[kt], bh, acc[q], 0, 0, 0);
            acc[q] = __builtin_amdgcn_mfma_f32_16x16x32_bf16(al[kt], bh, acc[q], 0, 0, 0);
            acc[q] = __builtin_amdgcn_mfma_f32_16x16x32_bf16(ah[kt], bl, acc[q], 0, 0, 0);
        }
    }

#pragma unroll
    for (int q = 0; q < 8; q++) {
        float bv = bias[col0 + q * 16 + col];
#pragma unroll
        for (int r = 0; r < 4; r++) {
            out[(size_t)(row0 + w * 16 + quad * 4 + r) * ldout + col0 + q * 16 + col]
                = acc[q][r] + bv;
        }
    }
}

// ---------------- MFMA GEMM (packed-A): A pre-packed in fragment order ----------------
// No fp32 read, no conversion, no LDS, no barrier; lane-sequential 16B loads.
__global__ __launch_bounds__(256) void gemm_mfp(
    const ushort* __restrict__ ahiP, const ushort* __restrict__ aloP,
    const ushort* __restrict__ bhi, const ushort* __restrict__ blo,
    const float* __restrict__ bias, float* __restrict__ out, const int ldout)
{
    constexpr int KT = 4;
    const int t = threadIdx.x;
    const int w = t >> 6, lane = t & 63;
    const int quad = lane >> 4, col = lane & 15;
    const int row0 = blockIdx.x * 64;
    const int col0 = blockIdx.y * 128;
    const size_t abase = (size_t)blockIdx.x * PTILE;

    short8 ah[KT], al[KT];
#pragma unroll
    for (int kt = 0; kt < KT; kt++) {
        const int off = ((kt * 4 + w) * 64 + lane) * 8;
        ah[kt] = *(const short8*)(ahiP + abase + off);
        al[kt] = *(const short8*)(aloP + abase + off);
    }

    f32x4 acc[8];
#pragma unroll
    for (int q = 0; q < 8; q++) acc[q] = (f32x4){0.f, 0.f, 0.f, 0.f};

#pragma unroll
    for (int q = 0; q < 8; q++) {
#pragma unroll
        for (int kt = 0; kt < KT; kt++) {
            const int f = ((((col0 >> 4) + q) * KT + kt) * 64 + lane) * 8;
            short8 bh = *(const short8*)(bhi + f);
            short8 bl = *(const short8*)(blo + f);
            acc[q] = __builtin_amdgcn_mfma_f32_16x16x32_bf16(ah[kt], bh, acc[q], 0, 0, 0);
            acc[q] = __builtin_amdgcn_mfma_f32_16x16x32_bf16(al[kt], bh, acc[q], 0, 0, 0);
            acc[q] = __builtin_amdgcn_mfma_f32_16x16x32_bf16(ah[kt], bl, acc[q], 0, 0, 0);
        }
    }

#pragma unroll
    for (int q = 0; q < 8; q++) {
        float bv = bias[col0 + q * 16 + col];
#pragma unroll
        for (int r = 0; r < 4; r++) {
            out[(size_t)(row0 + w * 16 + quad * 4 + r) * ldout + col0 + q * 16 + col]
                = acc[q][r] + bv;
        }
    }
}

// ---------------- packed-A W7 GEMM + row-dot: logit2[row] = relu(muP@W7+b7)·w5h ----------------
// mu arrives as packed bf16 hi/lo planes written by lstm8 (same f2bf values the
// staged path would derive -> bitwise identical). No staging at all.
__global__ __launch_bounds__(256) void gemm_w7dotp(
    const ushort* __restrict__ ahiP, const ushort* __restrict__ aloP,
    const ushort* __restrict__ bhi, const ushort* __restrict__ blo,
    const float* __restrict__ bias, const float* __restrict__ w5h,
    float* __restrict__ logit2)
{
    constexpr int KT = 4;
    const int t = threadIdx.x;
    const int w = t >> 6, lane = t & 63;
    const int quad = lane >> 4, col = lane & 15;
    const int row0 = blockIdx.x * 64;
    const size_t abase = (size_t)blockIdx.x * PTILE;

    short8 ah[KT], al[KT];
#pragma unroll
    for (int kt = 0; kt < KT; kt++) {
        const int off = ((kt * 4 + w) * 64 + lane) * 8;
        ah[kt] = *(const short8*)(ahiP + abase + off);
        al[kt] = *(const short8*)(aloP + abase + off);
    }

    f32x4 acc[8];
#pragma unroll
    for (int q = 0; q < 8; q++) acc[q] = (f32x4){0.f, 0.f, 0.f, 0.f};

#pragma unroll
    for (int q = 0; q < 8; q++) {
#pragma unroll
        for (int kt = 0; kt < KT; kt++) {
            const int f = ((q * KT + kt) * 64 + lane) * 8;
            short8 bh = *(const short8*)(bhi + f);
            short8 bl = *(const short8*)(blo + f);
            acc[q] = __builtin_amdgcn_mfma_f32_16x16x32_bf16(ah[kt], bh, acc[q], 0, 0, 0);
            acc[q] = __builtin_amdgcn_mfma_f32_16x16x32_bf16(al[kt], bh, acc[q], 0, 0, 0);
            acc[q] = __builtin_amdgcn_mfma_f32_16x16x32_bf16(ah[kt], bl, acc[q], 0, 0, 0);
        }
    }

    // epilogue: per-row dot with w5h over the 128 output channels
    float part0 = 0.f, part1 = 0.f, part2 = 0.f, part3 = 0.f;
#pragma unroll
    for (int q = 0; q < 8; q++) {
        float bv = bias[q * 16 + col];
        float wv = w5h[q * 16 + col];
        part0 += fmaxf(acc[q][0] + bv, 0.f) * wv;
        part1 += fmaxf(acc[q][1] + bv, 0.f) * wv;
        part2 += fmaxf(acc[q][2] + bv, 0.f) * wv;
        part3 += fmaxf(acc[q][3] + bv, 0.f) * wv;
    }
#pragma unroll
    for (int o = 1; o < 16; o <<= 1) {
        part0 += __shfl_xor(part0, o);
        part1 += __shfl_xor(part1, o);
        part2 += __shfl_xor(part2, o);
        part3 += __shfl_xor(part3, o);
    }
    if (col == 0) {
        const int rbase = row0 + w * 16 + quad * 4;
        logit2[rbase + 0] = part0;
        logit2[rbase + 1] = part1;
        logit2[rbase + 2] = part2;
        logit2[rbase + 3] = part3;
    }
}

// ---------------- fp32 GEMM (fallback path only) ----------------
template <int K>
__global__ __launch_bounds__(256) void gemm3(
    const float* __restrict__ x, const float* __restrict__ W,
    const float* __restrict__ b, float* __restrict__ out)
{
    __shared__ float Wsh[64 * 128];
    __shared__ float xT[64][132];
    const int t = threadIdx.x;
    const int row0 = blockIdx.x * 128;
    const int cg = t & 15;
    const int rg = t >> 4;
    float4 acc[8][2];
#pragma unroll
    for (int r = 0; r < 8; r++) {
        acc[r][0] = make_float4(0.f, 0.f, 0.f, 0.f);
        acc[r][1] = make_float4(0.f, 0.f, 0.f, 0.f);
    }
    for (int k0 = 0; k0 < K; k0 += 64) {
        for (int i = t * 4; i < 64 * 128; i += 1024)
            *(float4*)(Wsh + i) = *(const float4*)(W + (size_t)k0 * 128 + i);
        for (int i = t * 4; i < 128 * 64; i += 1024) {
            int r = i >> 6, k = i & 63;
            float4 v = *(const float4*)(x + (size_t)(row0 + r) * K + k0 + k);
            xT[k + 0][r] = v.x; xT[k + 1][r] = v.y;
            xT[k + 2][r] = v.z; xT[k + 3][r] = v.w;
        }
        __syncthreads();
#pragma unroll 2
        for (int k = 0; k < 64; k++) {
            float4 w0 = *(const float4*)(Wsh + k * 128 + cg * 8);
            float4 w1 = *(const float4*)(Wsh + k * 128 + cg * 8 + 4);
            float4 x0 = *(const float4*)(&xT[k][rg * 8]);
            float4 x1 = *(const float4*)(&xT[k][rg * 8 + 4]);
            float xv[8] = {x0.x, x0.y, x0.z, x0.w, x1.x, x1.y, x1.z, x1.w};
#pragma unroll
            for (int r = 0; r < 8; r++) {
                acc[r][0].x += xv[r] * w0.x; acc[r][0].y += xv[r] * w0.y;
                acc[r][0].z += xv[r] * w0.z; acc[r][0].w += xv[r] * w0.w;
                acc[r][1].x += xv[r] * w1.x; acc[r][1].y += xv[r] * w1.y;
                acc[r][1].z += xv[r] * w1.z; acc[r][1].w += xv[r] * w1.w;
            }
        }
        __syncthreads();
    }
    float4 bv0 = *(const float4*)(b + cg * 8);
    float4 bv1 = *(const float4*)(b + cg * 8 + 4);
#pragma unroll
    for (int r = 0; r < 8; r++) {
        float4 o0, o1;
        o0.x = acc[r][0].x + bv0.x; o0.y = acc[r][0].y + bv0.y;
        o0.z = acc[r][0].z + bv0.z; o0.w = acc[r][0].w + bv0.w;
        o1.x = acc[r][1].x + bv1.x; o1.y = acc[r][1].y + bv1.y;
        o1.z = acc[r][1].z + bv1.z; o1.w = acc[r][1].w + bv1.w;
        float* op = out + (size_t)(row0 + rg * 8 + r) * 128 + cg * 8;
        *(float4*)(op) = o0;
        *(float4*)(op + 4) = o1;
    }
}

// ---------------- fused GATv2 v5: 4 edges/wave (2 chains per 32-lane half) ----------------
// r7-proven loop (frozen). PACKED=true epilogue stores bf16 hi/lo planes in
// MFMA fragment order (bitwise identical downstream).
template <bool PACKED>
__global__ __launch_bounds__(256) void gat_fused_k(
    const float* __restrict__ xl, const int* __restrict__ rowptr,
    const int* __restrict__ srcs, const float* __restrict__ att,
    const float* __restrict__ bias, float* __restrict__ out,
    ushort* __restrict__ outhi, ushort* __restrict__ outlo, const int do_relu)
{
    const int lane = threadIdx.x & 63;
    const int q = lane & 31;           // channel group: ch q*4..q*4+3 (q<16 head0)
    const int h = lane >> 5;           // edge slot 0/1
    const int b = blockIdx.x;
    const int g = b & 7;
    const int j = b >> 3;
    const int jq = j / 250;
    const int jj = j - jq * 250;
    const int s = g + 8 * jq;
    const int n = s * NN + jj * 4 + (threadIdx.x >> 6);

    const float4 a4 = *(const float4*)(att + q * 4);
    const float4 xd = *(const float4*)(xl + (size_t)n * 128 + q * 4);
    const int i0 = rowptr[n], i1 = rowptr[n + 1];

    float mA = -1e30f, dA = 0.f, axA = 0.f, ayA = 0.f, azA = 0.f, awA = 0.f;
    float mB = -1e30f, dB = 0.f, axB = 0.f, ayB = 0.f, azB = 0.f, awB = 0.f;

    int iA = i0 + h, iB = i0 + h + 2;
    int svA = (iA < i1) ? srcs[iA] : 0;
    int svB = (iB < i1) ? srcs[iB] : 0;
    float4 xsA = *(const float4*)(xl + (size_t)svA * 128 + q * 4);
    float4 xsB = *(const float4*)(xl + (size_t)svB * 128 + q * 4);

    for (int base = i0; base < i1; base += 4) {
        const bool vA = (iA < i1), vB = (iB < i1);
        const int svA2 = (iA + 4 < i1) ? srcs[iA + 4] : 0;     // prefetch next iter
        const int svB2 = (iB + 4 < i1) ? srcs[iB + 4] : 0;
        const float4 xA2 = *(const float4*)(xl + (size_t)svA2 * 128 + q * 4);
        const float4 xB2 = *(const float4*)(xl + (size_t)svB2 * 128 + q * 4);

        float uA0 = xsA.x + xd.x, uA1 = xsA.y + xd.y;
        float uA2 = xsA.z + xd.z, uA3 = xsA.w + xd.w;
        float uB0 = xsB.x + xd.x, uB1 = xsB.y + xd.y;
        float uB2 = xsB.z + xd.z, uB3 = xsB.w + xd.w;
        float pA, pB;
        pA  = a4.x * fmaxf(uA0, 0.2f * uA0);
        pA += a4.y * fmaxf(uA1, 0.2f * uA1);
        pA += a4.z * fmaxf(uA2, 0.2f * uA2);
        pA += a4.w * fmaxf(uA3, 0.2f * uA3);
        pB  = a4.x * fmaxf(uB0, 0.2f * uB0);
        pB += a4.y * fmaxf(uB1, 0.2f * uB1);
        pB += a4.z * fmaxf(uB2, 0.2f * uB2);
        pB += a4.w * fmaxf(uB3, 0.2f * uB3);
        // head logit: sum within the 16-lane group; two independent chains
        pA += __shfl_xor(pA, 1);   pB += __shfl_xor(pB, 1);
        pA += __shfl_xor(pA, 2);   pB += __shfl_xor(pB, 2);
        pA += __shfl_xor(pA, 4);   pB += __shfl_xor(pB, 4);
        pA += __shfl_xor(pA, 8);   pB += __shfl_xor(pB, 8);

        float mnA = fmaxf(mA, vA ? pA : -1e30f);
        float mnB = fmaxf(mB, vB ? pB : -1e30f);
        float scA = __expf(mA - mnA), scB = __expf(mB - mnB);
        float wA = vA ? __expf(pA - mnA) : 0.f;
        float wB = vB ? __expf(pB - mnB) : 0.f;
        dA  = dA  * scA + wA;          dB  = dB  * scB + wB;
        axA = axA * scA + wA * xsA.x;  axB = axB * scB + wB * xsB.x;
        ayA = ayA * scA + wA * xsA.y;  ayB = ayB * scB + wB * xsB.y;
        azA = azA * scA + wA * xsA.z;  azB = azB * scB + wB * xsB.z;
        awA = awA * scA + wA * xsA.w;  awB = awB * scB + wB * xsB.w;
        mA = mnA; mB = mnB;
        xsA = xA2; xsB = xB2;
        iA += 4; iB += 4;
    }

    // merge chain B into chain A (within lane)
    float m1 = fmaxf(mA, mB);
    float sA = __expf(mA - m1), sB = __expf(mB - m1);
    float d  = dA * sA + dB * sB;
    float ax = axA * sA + axB * sB;
    float ay = ayA * sA + ayB * sB;
    float az = azA * sA + azB * sB;
    float aw = awA * sA + awB * sB;
    float m  = m1;

    // merge slot states (lanes l and l^32 hold the same channels)
    float m2 = __shfl_xor(m, 32);
    float d2 = __shfl_xor(d, 32);
    float bx = __shfl_xor(ax, 32);
    float by = __shfl_xor(ay, 32);
    float bz = __shfl_xor(az, 32);
    float bw = __shfl_xor(aw, 32);
    float mm = fmaxf(m, m2);
    float s1 = __expf(m - mm), s2 = __expf(m2 - mm);
    float den = d * s1 + d2 * s2;
    float inv = 1.f / den;
    float4 bv = *(const float4*)(bias + q * 4);
    float ox = (ax * s1 + bx * s2) * inv + bv.x;
    float oy = (ay * s1 + by * s2) * inv + bv.y;
    float oz = (az * s1 + bz * s2) * inv + bv.z;
    float ow = (aw * s1 + bw * s2) * inv + bv.w;
    if (do_relu) {
        ox = fmaxf(ox, 0.f); oy = fmaxf(oy, 0.f);
        oz = fmaxf(oz, 0.f); ow = fmaxf(ow, 0.f);
    }
    if (lane < 32) {
        if (PACKED) {
            // fragment-order packed store (channels q*4..q*4+3 share one 8B slot)
            const int tile = n >> 6, r = n & 63;
            const int rw = r >> 4, rcol = r & 15;
            const size_t idx = (size_t)tile * PTILE +
                (size_t)((((q >> 3) * 4 + rw) * 64 + ((q >> 1) & 3) * 16 + rcol) * 8
                         + (q & 1) * 4);
            ushort h0 = f2bf(ox), h1 = f2bf(oy), h2 = f2bf(oz), h3 = f2bf(ow);
            ushort l0 = f2bf(ox - bf2f(h0)), l1 = f2bf(oy - bf2f(h1));
            ushort l2 = f2bf(oz - bf2f(h2)), l3 = f2bf(ow - bf2f(h3));
            *(uint2*)(outhi + idx) = make_uint2((uint)h0 | ((uint)h1 << 16),
                                                (uint)h2 | ((uint)h3 << 16));
            *(uint2*)(outlo + idx) = make_uint2((uint)l0 | ((uint)l1 << 16),
                                                (uint)l2 | ((uint)l3 << 16));
        } else {
            *(float4*)(out + (size_t)n * 128 + q * 4) = make_float4(ox, oy, oz, ow);
        }
    }
}

// ---------------- LSTM weight packing (fallback path) ----------------
__global__ void build_wq_k(const float* __restrict__ Wih, const float* __restrict__ Whh,
                           float4* __restrict__ WQa, float4* __restrict__ WQb) {
    int id = blockIdx.x * 256 + threadIdx.x;
    if (id < 64 * 256) {
        int kp = id >> 8, t = id & 255;
        int j1 = t, j2 = t + 256;
        WQa[id] = make_float4(Wih[(size_t)j1 * 128 + 2 * kp], Whh[(size_t)j1 * 128 + 2 * kp],
                              Wih[(size_t)j1 * 128 + 2 * kp + 1], Whh[(size_t)j1 * 128 + 2 * kp + 1]);
        WQb[id] = make_float4(Wih[(size_t)j2 * 128 + 2 * kp], Whh[(size_t)j2 * 128 + 2 * kp],
                              Wih[(size_t)j2 * 128 + 2 * kp + 1], Whh[(size_t)j2 * 128 + 2 * kp + 1]);
    }
}

// ---- fallback LSTM (round-3, small-ws only) ----
#define LSTM_GROUP(buf, gbase)                                                     \
    _Pragma("unroll")                                                              \
    for (int i_ = 0; i_ < 4; i_++) {                                               \
        const int kp_ = (gbase) * 4 + i_;                                          \
        const float4 qa_ = buf[i_];                                                \
        const float4 qb_ = buf[4 + i_];                                            \
        _Pragma("unroll")                                                          \
        for (int n_ = 0; n_ < 4; n_++) {                                           \
            const float sx0_ = rdlane(xr[n_].x, kp_);                              \
            const float sh0_ = rdlane(hr[n_].x, kp_);                              \
            const float sx1_ = rdlane(xr[n_].y, kp_);                              \
            const float sh1_ = rdlane(hr[n_].y, kp_);                              \
            acc1[n_] += sx0_ * qa_.x + sh0_ * qa_.y + sx1_ * qa_.z + sh1_ * qa_.w; \
            acc2[n_] += sx0_ * qb_.x + sh0_ * qb_.y + sx1_ * qb_.z + sh1_ * qb_.w; \
        }                                                                          \
    }

__global__ __launch_bounds__(256, 1) void lstm_k(
    float* __restrict__ mu, const float4* __restrict__ WQa, const float4* __restrict__ WQb,
    const float* __restrict__ bih, const float* __restrict__ bhh,
    const float* __restrict__ h0, const float* __restrict__ c0,
    float* __restrict__ hT, float* __restrict__ cT)
{
    const int t = threadIdx.x, lane = t & 63;
    const int n0 = blockIdx.x * 4;
    __shared__ float hsh[4][128];
    __shared__ float gsh[4][512];
    const float b1 = bih[t] + bhh[t];
    const float b2 = bih[t + 256] + bhh[t + 256];
    float creg[2];
#pragma unroll
    for (int q = 0; q < 2; q++) {
        int id = t + 256 * q;
        creg[q] = c0[(size_t)(n0 + (id >> 7)) * 128 + (id & 127)];
    }
    for (int i = t; i < 512; i += 256)
        hsh[i >> 7][i & 127] = h0[(size_t)(n0 + (i >> 7)) * 128 + (i & 127)];

    const float4* pA = WQa + t;
    const float4* pB = WQb + t;

    float2 xr[4], xnx[4];
#pragma unroll
    for (int n = 0; n < 4; n++)
        xr[n] = *(const float2*)(mu + (size_t)n0 * 128 + n * 128 + lane * 2);
    __syncthreads();

    for (int s = 0; s < SQ; s++) {
        float* xrow = mu + ((size_t)s * NN + n0) * 128;
        float2 hr[4];
#pragma unroll
        for (int n = 0; n < 4; n++) hr[n] = *(const float2*)(&hsh[n][lane * 2]);

        float4 bufA[8], bufB[8];
#pragma unroll
        for (int i = 0; i < 4; i++) { bufA[i] = pA[i * 256]; bufA[4 + i] = pB[i * 256]; }

        if (s + 1 < SQ) {
            const float* xrow2 = mu + ((size_t)(s + 1) * NN + n0) * 128;
#pragma unroll
            for (int n = 0; n < 4; n++) xnx[n] = *(const float2*)(xrow2 + n * 128 + lane * 2);
        }

        float acc1[4], acc2[4];
#pragma unroll
        for (int n = 0; n < 4; n++) { acc1[n] = b1; acc2[n] = b2; }

        for (int g = 0; g < 16; g += 2) {
#pragma unroll
            for (int i = 0; i < 4; i++) {
                bufB[i]     = pA[((g + 1) * 4 + i) * 256];
                bufB[4 + i] = pB[((g + 1) * 4 + i) * 256];
            }
            LSTM_GROUP(bufA, g)
            if (g < 14) {
#pragma unroll
                for (int i = 0; i < 4; i++) {
                    bufA[i]     = pA[((g + 2) * 4 + i) * 256];
                    bufA[4 + i] = pB[((g + 2) * 4 + i) * 256];
                }
            }
            LSTM_GROUP(bufB, g + 1)
        }

#pragma unroll
        for (int n = 0; n < 4; n++) { gsh[n][t] = acc1[n]; gsh[n][t + 256] = acc2[n]; }
        __syncthreads();
#pragma unroll
        for (int q = 0; q < 2; q++) {
            int id = t + 256 * q;
            int n = id >> 7, e = id & 127;
            float iv = gsh[n][e], fv = gsh[n][128 + e];
            float gv = gsh[n][256 + e], ov = gsh[n][384 + e];
            float c = sigm(fv) * creg[q] + sigm(iv) * tanh_f(gv);
            float h = sigm(ov) * tanh_f(c);
            creg[q] = c;
            hsh[n][e] = h;
            xrow[n * 128 + e] = h;
            if (s == SQ - 1) {
                hT[(size_t)(n0 + n) * 128 + e] = h;
                cT[(size_t)(n0 + n) * 128 + e] = c;
            }
        }
#pragma unroll
        for (int n = 0; n < 4; n++) xr[n] = xnx[n];
        __syncthreads();
    }
}

// ---------------- MFMA LSTM v8p (big-ws path) — lstm8 + packed-plane mu output ----------------
// Identical compute to the proven lstm8 (87-90us). Only the mu store changes:
// instead of fp32 mu it writes the ALREADY-COMPUTED bf16 hi/lo (hh/hl, same
// values stored in hbuf) into fragment-order planes for the packed W7 head.
// Same bytes per element (2+2 vs 4); head then needs no staging at all.
__global__ __launch_bounds__(512, 2) void lstm8_k(
    ushort* __restrict__ muhi, ushort* __restrict__ mulo,
    const float* __restrict__ xC, const ushort* __restrict__ Bfrag,
    const float* __restrict__ h0, const float* __restrict__ c0,
    float* __restrict__ hT, float* __restrict__ cT)
{
    const int t = threadIdx.x;
    const int w = t >> 6, lane = t & 63;
    const int quad = lane >> 4, col = lane & 15;
    const int n0 = blockIdx.x * 4;                // 250 * 4 = 1000 exactly
    const int enode = t >> 7;                     // epilogue node 0..3
    const int ech   = t & 127;                    // epilogue channel 0..127

    __shared__ __align__(16) ushort hbuf[2][2][16 * 136];   // [pingpong][hi/lo]
    __shared__ float gsh[4][512];                           // gate preacts (h@Whh)

    // B fragments: wave w owns gate tiles {g4*8 + w}, g4 = i,f,g,o group
    short8 bf[4][4];
#pragma unroll
    for (int g4 = 0; g4 < 4; g4++)
#pragma unroll
        for (int kt = 0; kt < 4; kt++) {
            int tile = g4 * 8 + w;
            bf[g4][kt] = *(const short8*)(Bfrag + (((tile * 4 + kt) * 64 + lane) << 3));
        }

    // init hbuf: rows 0..3 = h0, rows 4..15 = 0 (stay 0 forever); both buffers
    for (int i = t; i < 2048; i += 512) {
        int node = i >> 7, ee = i & 127;
        float v = (node < 4) ? h0[(size_t)(n0 + node) * 128 + ee] : 0.f;
        ushort hh = f2bf(v), hl = f2bf(v - bf2f(hh));
        hbuf[0][0][node * 136 + ee] = hh; hbuf[0][1][node * 136 + ee] = hl;
        hbuf[1][0][node * 136 + ee] = hh; hbuf[1][1][node * 136 + ee] = hl;
    }
    float cst = c0[(size_t)(n0 + enode) * 128 + ech];

    // packed-plane sub-index for this thread's channel (row part added per step)
    const int pch = (((ech >> 5) * 4) * 64 + ((ech >> 3) & 3) * 16) * 8 + (ech & 7);

    // preload step-0 xC gate preacts for this thread's (node, channel)
    float xcr[4], xcn[4];
#pragma unroll
    for (int g4 = 0; g4 < 4; g4++)
        xcr[g4] = xC[((size_t)(n0 + enode)) * 512 + g4 * 128 + ech];
    __syncthreads();

    int p = 0;
    for (int s = 0; s < SQ; s++) {
        // 1. issue next step's xC loads — consumed NEXT iteration
        if (s + 1 < SQ) {
            const float* xn = xC + ((size_t)(s + 1) * NN + n0 + enode) * 512;
#pragma unroll
            for (int g4 = 0; g4 < 4; g4++)
                xcn[g4] = xn[g4 * 128 + ech];
        }

        // 2. A fragments from current h buffer (row = col lane; rows>=4 are 0)
        short8 ahi[4], alo[4];
#pragma unroll
        for (int kt = 0; kt < 4; kt++) {
            ahi[kt] = *(const short8*)(&hbuf[p][0][col * 136 + kt * 32 + quad * 8]);
            alo[kt] = *(const short8*)(&hbuf[p][1][col * 136 + kt * 32 + quad * 8]);
        }

        // 3. MFMA: 32 issues, 4 independent acc chains
        f32x4 acc[4];
#pragma unroll
        for (int g4 = 0; g4 < 4; g4++) acc[g4] = (f32x4){0.f, 0.f, 0.f, 0.f};
#pragma unroll
        for (int kt = 0; kt < 4; kt++) {
#pragma unroll
            for (int g4 = 0; g4 < 4; g4++)
                acc[g4] = __builtin_amdgcn_mfma_f32_16x16x32_bf16(ahi[kt], bf[g4][kt], acc[g4], 0, 0, 0);
#pragma unroll
            for (int g4 = 0; g4 < 4; g4++)
                acc[g4] = __builtin_amdgcn_mfma_f32_16x16x32_bf16(alo[kt], bf[g4][kt], acc[g4], 0, 0, 0);
        }

        // 4. scatter valid rows (nodes 0..3 live in quad-0 lanes) to gsh
        if (quad == 0) {
#pragma unroll
            for (int g4 = 0; g4 < 4; g4++)
#pragma unroll
                for (int r = 0; r < 4; r++)
                    gsh[r][(g4 * 8 + w) * 16 + col] = acc[g4][r];
        }
        __syncthreads();

        // 5. dense epilogue: each thread one (node, channel)
        {
            float iv = gsh[enode][0 * 128 + ech] + xcr[0];
            float fv = gsh[enode][1 * 128 + ech] + xcr[1];
            float gv = gsh[enode][2 * 128 + ech] + xcr[2];
            float ov = gsh[enode][3 * 128 + ech] + xcr[3];
            float c = sigm(fv) * cst + sigm(iv) * tanh2(gv);
            float h = sigm(ov) * tanh2(c);
            cst = c;
            const int pn = p ^ 1;
            ushort hh = f2bf(h);
            ushort hl = f2bf(h - bf2f(hh));
            hbuf[pn][0][enode * 136 + ech] = hh;
            hbuf[pn][1][enode * 136 + ech] = hl;
            // packed-plane mu store (same hh/hl values; fragment order)
            {
                const int r = s * NN + n0 + enode;
                const size_t pidx = (size_t)(r >> 6) * PTILE +
                    (size_t)(pch + (((r >> 4) & 3) * 64 + (r & 15)) * 8);
                muhi[pidx] = hh;
                mulo[pidx] = hl;
            }
            if (s == SQ - 1) {
                hT[(size_t)(n0 + enode) * 128 + ech] = h;
                cT[(size_t)(n0 + enode) * 128 + ech] = c;
            }
            p = pn;
        }
#pragma unroll
        for (int g4 = 0; g4 < 4; g4++) xcr[g4] = xcn[g4];
        __syncthreads();
    }
}

// ---------------- head: logit2[row] (fallback path; gs/b5 cancel in softmax) ----------------
__global__ __launch_bounds__(256) void rowdot_k(
    const float* __restrict__ la, const float* __restrict__ w5,
    float* __restrict__ out)
{
    const int lane = threadIdx.x & 63;
    const int row = blockIdx.x * 4 + (threadIdx.x >> 6);
    float2 v = *(const float2*)(la + (size_t)row * 128 + lane * 2);
    float2 w = *(const float2*)(w5 + 128 + lane * 2);
    float x = fmaxf(v.x, 0.f) * w.x + fmaxf(v.y, 0.f) * w.y;
#pragma unroll
    for (int o = 32; o; o >>= 1) x += __shfl_down(x, o);
    if (lane == 0) out[row] = x;
}

// ---------------- masked softmax per sequence step ----------------
__device__ __forceinline__ bool reach_at(const void* reach, int mode, int idx) {
    if (mode == 0) return ((const int*)reach)[idx] != 0;
    if (mode == 1) return ((const unsigned char*)reach)[idx] != 0;
    return ((const float*)reach)[idx] != 0.f;
}
__global__ __launch_bounds__(256) void softmax_k(
    const float* __restrict__ lg, const void* __restrict__ reach,
    const int* __restrict__ mode, float* __restrict__ prob)
{
    const int s = blockIdx.x, t = threadIdx.x;
    const int m = *mode;
    __shared__ float red[256];
    float mx = -1e30f;
    for (int i = t; i < NN; i += 256) {
        int idx = s * NN + i;
        if (reach_at(reach, m, idx)) mx = fmaxf(mx, lg[idx]);
    }
    red[t] = mx;
    __syncthreads();
    for (int o = 128; o; o >>= 1) {
        if (t < o) red[t] = fmaxf(red[t], red[t + o]);
        __syncthreads();
    }
    mx = red[0];
    __syncthreads();
    float sum = 0.f;
    for (int i = t; i < NN; i += 256) {
        int idx = s * NN + i;
        float v = reach_at(reach, m, idx) ? __expf(lg[idx] - mx) : 0.f;
        prob[idx] = v;
        sum += v;
    }
    red[t] = sum;
    __syncthreads();
    for (int o = 128; o; o >>= 1) {
        if (t < o) red[t] += red[t + o];
        __syncthreads();
    }
    float inv = 1.f / red[0];
    for (int i = t; i < NN; i += 256) prob[s * NN + i] *= inv;
}

// ---------------- driver ----------------
extern "C" void kernel_launch(void* const* d_in, const int* in_sizes, int n_in,
                              void* d_out, int out_size, void* d_ws, size_t ws_size,
                              hipStream_t stream) {
    const float* nfm   = (const float*)d_in[0];
    const int*   ei    = (const int*)d_in[1];
    const void*  reach = d_in[2];
    const float* h0    = (const float*)d_in[3];
    const float* c0    = (const float*)d_in[4];
    const float* W1    = (const float*)d_in[5];
    const float* b1    = (const float*)d_in[6];
    const float* att1  = (const float*)d_in[7];
    const float* bias1 = (const float*)d_in[8];
    const float* Wl    = (const float*)d_in[9];
    const float* bl    = (const float*)d_in[10];
    const float* attl  = (const float*)d_in[11];
    const float* biasl = (const float*)d_in[12];
    const float* Wih   = (const float*)d_in[13];
    const float* Whh   = (const float*)d_in[14];
    const float* bih   = (const float*)d_in[15];
    const float* bhh   = (const float*)d_in[16];
    const float* W6    = (const float*)d_in[17];
    const float* b6    = (const float*)d_in[18];
    const float* W7    = (const float*)d_in[19];
    const float* b7    = (const float*)d_in[20];
    const float* w5    = (const float*)d_in[21];
    const float* b5    = (const float*)d_in[22];
    (void)W6; (void)b6; (void)b5;   // gs term and b5 cancel in the node softmax

    char* ws = (char*)d_ws;
    const bool bigws = (ws_size >= WS2_NEED);

    float*  xA     = (float*)(ws + WS_XA);
    ushort* phi    = (ushort*)(ws + WS_PHI);
    ushort* plo    = (ushort*)(ws + WS_PLO);
    float*  xB     = (float*)(ws + WS_XB);
    int*    rowptr = (int*)(ws + WS_ROWPTR);
    int*    cursor = (int*)(ws + WS_CURSOR);
    int*    srcs   = (int*)(ws + WS_SRCS);
    int*    incl   = (int*)(ws + WS_INCL);
    int*    bsum   = (int*)(ws + WS_BSUM);
    int*    modep  = bigws ? (int*)(ws + WS2_MODE)     : (int*)(ws + WS_MODE);
    float*  logit2 = bigws ? (float*)(ws + WS2_LOGIT2) : (float*)(ws + WS_LOGIT2);
    // big-ws extras
    float*  xC     = (float*)(ws + WS2_XC);
    ushort* Bfrag  = (ushort*)(ws + WS2_BFRAG);
    ushort* ghi    = (ushort*)(ws + WS2_GHI);
    ushort* glo    = (ushort*)(ws + WS2_GLO);
    float*  b512   = (float*)(ws + WS2_B512);
    // fallback extras
    float4* WQa    = (float4*)(ws + WS_WQA);
    float4* WQb    = (float4*)(ws + WS_WQB);

    float* prob = (float*)d_out;
    float* hT   = (float*)d_out + 64000;
    float* cT   = (float*)d_out + 192000;

    // setup
    detect_mode_k<<<1, 1024, 0, stream>>>((const unsigned char*)reach, modep);
    zero_ints_k<<<250, 256, 0, stream>>>(cursor, NT);
    hist_k<<<2250, 256, 0, stream>>>(ei, cursor);
    scan1_k<<<250, 256, 0, stream>>>(cursor, incl, bsum);
    scan3_k<<<250, 256, 0, stream>>>(incl, bsum, rowptr, cursor);
    fill_k<<<2250, 256, 0, stream>>>(ei, cursor, srcs);
    if (bigws) {
        build_all_k<<<866, 256, 0, stream>>>(Whh, bih, bhh, W1, Wl, Wih, W7,
                                             Bfrag, b512, ghi, glo);
    } else {
        build_wq_k<<<64, 256, 0, stream>>>(Wih, Whh, WQa, WQb);
    }

    // 5 GATv2 layers
    for (int l = 0; l < 5; l++) {
        const float* att  = (l == 0) ? att1  : attl  + (l - 1) * 128;
        const float* bias = (l == 0) ? bias1 : biasl + (l - 1) * 128;
        if (bigws) {
            if (l == 0)
                gemm_mf<2><<<dim3(1000, 1), 256, 0, stream>>>(nfm, ghi + G_W1, glo + G_W1, b1, xB, 128);
            else
                gemm_mfp<<<dim3(1000, 1), 256, 0, stream>>>(phi, plo,
                                                            ghi + G_WL + (l - 1) * 16384,
                                                            glo + G_WL + (l - 1) * 16384,
                                                            bl + (l - 1) * 128, xB, 128);
            // gat writes packed bf16 hi/lo planes (fragment order) for next consumer
            gat_fused_k<true><<<16000, 256, 0, stream>>>(xB, rowptr, srcs, att, bias,
                                                         nullptr, phi, plo, (l < 4) ? 1 : 0);
        } else {
            if (l == 0)
                gemm3<64><<<500, 256, 0, stream>>>(nfm, W1, b1, xB);
            else
                gemm3<128><<<500, 256, 0, stream>>>(xA, Wl + (size_t)(l - 1) * 128 * 128,
                                                    bl + (l - 1) * 128, xB);
            gat_fused_k<false><<<16000, 256, 0, stream>>>(xB, rowptr, srcs, att, bias,
                                                          xA, nullptr, nullptr, (l < 4) ? 1 : 0);
        }
    }

    // LSTM
    if (bigws) {
        // xC = mu @ Wih^T + (bih+bhh); A read directly from packed planes (gat L5)
        gemm_mfp<<<dim3(1000, 4), 256, 0, stream>>>(phi, plo, ghi + G_PROJ, glo + G_PROJ,
                                                    b512, xC, 512);
        // lstm8 overwrites phi/plo (now dead) with packed mu planes for the head
        lstm8_k<<<250, 512, 0, stream>>>(phi, plo, xC, Bfrag, h0, c0, hT, cT);
    } else {
        lstm_k<<<250, 256, 0, stream>>>(xA, WQa, WQb, bih, bhh, h0, c0, hT, cT);
    }

    // head: logits (gs/meanpool term + b5 cancel in the per-row softmax)
    if (bigws) {
        gemm_w7dotp<<<1000, 256, 0, stream>>>(phi, plo, ghi + G_W7, glo + G_W7,
                                              b7, w5 + 128, logit2);
    } else {
        gemm3<128><<<500, 256, 0, stream>>>(xA, W7, b7, xB);
        rowdot_k<<<16000, 256, 0, stream>>>(xB, w5, logit2);
    }
    softmax_k<<<64, 256, 0, stream>>>(logit2, reach, modep, prob);
}

// Round 14
// 612.315 us; speedup vs baseline: 1.0081x; 1.0081x over previous
//
#include <hip/hip_runtime.h>
#include <hip/hip_bf16.h>

// ---------------- problem constants ----------------
#define SQ   64        // seq len
#define NN   1000      // nodes per graph
#define NT   64000     // total nodes
#define EE   128       // emb dim
#define EG   512000    // graph edges (no self loops)
#define ET   576000    // edges + self loops

// ---------------- workspace layout (bytes) ----------------
// common / fallback region (<71 MB)
#define WS_XA      0ull          // 32,768,000  float[NT*128]  x ping (mu lives here)
#define WS_PHI     0ull          // 16,384,000  ushort hi-plane (packed A, aliases XA)
#define WS_PLO     16500000ull   // 16,384,000  ushort lo-plane (packed A, aliases XA)
#define WS_XB      33000000ull   // 32,768,000  float[NT*128]  x pong (xl / la)
#define WS_ROWPTR  66000000ull   // 256,004     int[NT+1]
#define WS_CURSOR  66300000ull   // 256,000     int[NT]
#define WS_SRCS    66600000ull   // 2,304,000   int[ET]  (src node id, dst-grouped)
#define WS_INCL    69000000ull   // 256,000     int[NT]
#define WS_BSUM    69300000ull   // 1,024       int[250]
#define WS_MODE    69304096ull   // 4           int
#define WS_WQA     70000000ull   // 262,144     float4[64*256]  (fallback LSTM)
#define WS_WQB     70262144ull   // 262,144     float4[64*256]  (fallback LSTM)
#define WS_LOGIT2  70700000ull   // 256,000     float[NT]
// big-ws region: xC aliases xB + CSR (disjoint lifetimes)
#define WS2_XC     33000000ull   // 131,072,000 float[NT*512]  gate preacts (row-major)
#define WS2_BFRAG  164100000ull  // 131,072     ushort bf16 Whh B-fragments (LSTM)
#define WS2_GHI    164300000ull  // 311,296     ushort GEMM W fragments (hi)
#define WS2_GLO    164650000ull  // 311,296     ushort GEMM W fragments (lo)
#define WS2_B512   165000000ull  // 2,048       float[512]     bih+bhh
#define WS2_MODE   165010000ull  // 4
#define WS2_LOGIT2 165100000ull  // 256,000
#define WS2_NEED   165360000ull
// GEMM fragment sub-offsets (ushort elements within GHI/GLO)
#define G_W1    0        // 64x128  -> 8192
#define G_WL    8192     // 4 x 128x128 -> 16384 each
#define G_PROJ  73728    // 128x512 -> 65536
#define G_W7    139264   // 128x128 -> 16384
// packed-A plane: 1000 tiles x 8192 ushorts (K=128 fragment order)
#define PTILE   8192

typedef __attribute__((ext_vector_type(8))) short short8;   // 8 bf16 (4 VGPRs)
typedef __attribute__((ext_vector_type(4))) float f32x4;

// ---------------- helpers ----------------
__device__ __forceinline__ float rdlane(float v, int l) {
    return __int_as_float(__builtin_amdgcn_readlane(__float_as_int(v), l));
}
__device__ __forceinline__ float sigm(float x) { return 1.0f / (1.0f + __expf(-x)); }
__device__ __forceinline__ float tanh_f(float x) {
    x = fminf(fmaxf(x, -30.0f), 30.0f);
    float e = __expf(2.0f * x);
    return (e - 1.0f) / (e + 1.0f);
}
__device__ __forceinline__ float tanh2(float x) {   // 2*sigmoid(2x)-1, inf-safe
    return 2.0f / (1.0f + __expf(-2.0f * x)) - 1.0f;
}
__device__ __forceinline__ ushort f2bf(float x) {   // round-to-nearest-even bf16
    unsigned u = __float_as_uint(x);
    unsigned r = (u + 0x7FFFu + ((u >> 16) & 1u)) >> 16;
    return (ushort)r;
}
__device__ __forceinline__ float bf2f(ushort h) {
    return __uint_as_float(((unsigned)h) << 16);
}

// ---------------- reachable dtype detection ----------------
__global__ void detect_mode_k(const unsigned char* __restrict__ p, int* __restrict__ mode) {
    __shared__ int f0, f3;
    const int t = threadIdx.x;
    if (t == 0) { f0 = 0; f3 = 0; }
    __syncthreads();
    int l0 = 0, l3 = 0;
    for (int i = t; i < 16000; i += 1024) {
        if (p[4 * i])     l0 = 1;
        if (p[4 * i + 3]) l3 = 1;
    }
    if (l0) atomicOr(&f0, 1);
    if (l3) atomicOr(&f3, 1);
    __syncthreads();
    if (t == 0) {
        int m;
        if (f0 && f3)      m = 1;  // bool bytes
        else if (f0)       m = 0;  // int32
        else               m = 2;  // float32
        *mode = m;
    }
}

// ---------------- CSR construction (dst-grouped src list; built once) ----------------
__global__ void zero_ints_k(int* __restrict__ p, int n) {
    int i = blockIdx.x * 256 + threadIdx.x;
    if (i < n) p[i] = 0;
}
__global__ void hist_k(const int* __restrict__ ei, int* __restrict__ deg) {
    int e = blockIdx.x * 256 + threadIdx.x;
    if (e < ET) {
        int d = (e < EG) ? ei[EG + e] : (e - EG);
        atomicAdd(deg + d, 1);
    }
}
__global__ void scan1_k(const int* __restrict__ deg, int* __restrict__ incl, int* __restrict__ bsum) {
    __shared__ int sh[256];
    const int t = threadIdx.x;
    const int i = blockIdx.x * 256 + t;
    sh[t] = deg[i];
    __syncthreads();
    for (int o = 1; o < 256; o <<= 1) {
        int add = (t >= o) ? sh[t - o] : 0;
        __syncthreads();
        sh[t] += add;
        __syncthreads();
    }
    incl[i] = sh[t];
    if (t == 255) bsum[blockIdx.x] = sh[255];
}
// scan3 with INLINE block-offset reduction (absorbs the old scan2's single-block
// launch bubble). rowptr bitwise identical to the scan2+scan3 pair.
__global__ void scan3_k(const int* __restrict__ incl, const int* __restrict__ bsum,
                        int* __restrict__ rowptr, int* __restrict__ cursor_deg) {
    __shared__ int sh[256];
    const int t = threadIdx.x;
    const int i = blockIdx.x * 256 + t;
    sh[t] = (t < blockIdx.x) ? bsum[t] : 0;   // blockIdx.x <= 249 < 256
    __syncthreads();
    for (int o = 128; o; o >>= 1) {
        if (t < o) sh[t] += sh[t + o];
        __syncthreads();
    }
    const int boff = sh[0];
    int total = incl[i] + boff;
    int excl  = total - cursor_deg[i];
    rowptr[i] = excl;
    cursor_deg[i] = excl;                 // becomes fill cursor
    if (i == NT - 1) rowptr[NT] = total;
}
__global__ void fill_k(const int* __restrict__ ei, int* __restrict__ cursor, int* __restrict__ srcs) {
    int e = blockIdx.x * 256 + threadIdx.x;
    if (e < ET) {
        int s_, d_;
        if (e < EG) { s_ = ei[e]; d_ = ei[EG + e]; }
        else        { s_ = e - EG; d_ = s_; }
        int p = atomicAdd(cursor + d_, 1);
        srcs[p] = s_;
    }
}

// ---------------- fused weight-prep (big-ws): bfrag + bias512 + 6 gfrags ----------------
__device__ __forceinline__ void gfrag_dev(const float* __restrict__ src, const int ks,
                                          const int ns, const int K,
                                          ushort* __restrict__ dhi, ushort* __restrict__ dlo,
                                          const int total, const int id) {
    if (id < total) {
        int j = id & 7, lane = (id >> 3) & 63;
        int f = id >> 9;
        int KT = K >> 5;
        int nt = f / KT, kt = f - nt * KT;
        int n = nt * 16 + (lane & 15);
        int k = kt * 32 + ((lane >> 4) << 3) + j;
        float v = src[(size_t)k * ks + (size_t)n * ns];
        ushort h = f2bf(v);
        dhi[id] = h;
        dlo[id] = f2bf(v - bf2f(h));
    }
}
__global__ void build_all_k(const float* __restrict__ Whh, const float* __restrict__ bih,
                            const float* __restrict__ bhh, const float* __restrict__ W1,
                            const float* __restrict__ Wl, const float* __restrict__ Wih,
                            const float* __restrict__ W7, ushort* __restrict__ Bfrag,
                            float* __restrict__ b512, ushort* __restrict__ ghi,
                            ushort* __restrict__ glo) {
    const int b = blockIdx.x, t = threadIdx.x;
    if (b < 256) {                       // Whh B-fragments (LSTM), 65536 ids
        int id = b * 256 + t;
        int j = id & 7, lane = (id >> 3) & 63, kt = (id >> 9) & 3, tile = id >> 11;
        int gate = tile * 16 + (lane & 15);
        int k = kt * 32 + ((lane >> 4) << 3) + j;
        Bfrag[id] = f2bf(Whh[(size_t)gate * 128 + k]);
    } else if (b < 258) {                // bias512
        int i = (b - 256) * 256 + t;
        if (i < 512) b512[i] = bih[i] + bhh[i];
    } else if (b < 290) {                // W1: 64x128
        gfrag_dev(W1, 128, 1, 64, ghi + G_W1, glo + G_W1, 8192, (b - 258) * 256 + t);
    } else if (b < 546) {                // 4x Wl: 128x128 each, 64 blocks apiece
        int bb = b - 290;
        int i = bb >> 6;
        gfrag_dev(Wl + (size_t)i * 16384, 128, 1, 128,
                  ghi + G_WL + i * 16384, glo + G_WL + i * 16384, 16384, (bb & 63) * 256 + t);
    } else if (b < 802) {                // Wih: 128x512 (transposed access)
        gfrag_dev(Wih, 1, 128, 128, ghi + G_PROJ, glo + G_PROJ, 65536, (b - 546) * 256 + t);
    } else {                             // W7: 128x128
        gfrag_dev(W7, 128, 1, 128, ghi + G_W7, glo + G_W7, 16384, (b - 802) * 256 + t);
    }
}

// ---------------- MFMA GEMM (staged-A): out = x @ W + bias, split bf16 hi/lo ----------------
// Used where A is fp32 in memory (layer-1 gemm from nfm; staged w7dot head).
template <int KT>
__global__ __launch_bounds__(256) void gemm_mf(
    const float* __restrict__ x, const ushort* __restrict__ bhi,
    const ushort* __restrict__ blo, const float* __restrict__ bias,
    float* __restrict__ out, const int ldout)
{
    constexpr int K = KT * 32;
    __shared__ __align__(16) ushort ahi_s[KT * 4 * 64 * 8];
    __shared__ __align__(16) ushort alo_s[KT * 4 * 64 * 8];
    const int t = threadIdx.x;
    const int w = t >> 6, lane = t & 63;
    const int quad = lane >> 4, col = lane & 15;
    const int row0 = blockIdx.x * 64;
    const int col0 = blockIdx.y * 128;

    {
        const int r  = t >> 2;            // row 0..63
        const int kc = (t & 3) * (K / 4); // channel quarter
        const int rw = r >> 4, rcol = r & 15;
        const float* xr = x + (size_t)(row0 + r) * K + kc;
#pragma unroll
        for (int k = 0; k < K / 4; k += 4) {
            const int ch = kc + k;
            const int idx = (((ch >> 5) * 4 + rw) * 64 + ((ch >> 3) & 3) * 16 + rcol) * 8
                            + (ch & 7);
            float4 v = *(const float4*)(xr + k);
            ushort h0_ = f2bf(v.x), h1_ = f2bf(v.y), h2_ = f2bf(v.z), h3_ = f2bf(v.w);
            ushort l0_ = f2bf(v.x - bf2f(h0_)), l1_ = f2bf(v.y - bf2f(h1_));
            ushort l2_ = f2bf(v.z - bf2f(h2_)), l3_ = f2bf(v.w - bf2f(h3_));
            *(uint2*)(ahi_s + idx) = make_uint2((uint)h0_ | ((uint)h1_ << 16),
                                                (uint)h2_ | ((uint)h3_ << 16));
            *(uint2*)(alo_s + idx) = make_uint2((uint)l0_ | ((uint)l1_ << 16),
                                                (uint)l2_ | ((uint)l3_ << 16));
        }
    }
    __syncthreads();

    short8 ah[KT], al[KT];
#pragma unroll
    for (int kt = 0; kt < KT; kt++) {
        const int off = ((kt * 4 + w) * 64 + lane) * 8;
        ah[kt] = *(const short8*)(ahi_s + off);
        al[kt] = *(const short8*)(alo_s + off);
    }

    f32x4 acc[8];
#pragma unroll
    for (int q = 0; q < 8; q++) acc[q] = (f32x4){0.f, 0.f, 0.f, 0.f};

#pragma unroll
    for (int q = 0; q < 8; q++) {
#pragma unroll
        for (int kt = 0; kt < KT; kt++) {
            const int f = ((((col0 >> 4) + q) * KT + kt) * 64 + lane) * 8;
            short8 bh = *(const short8*)(bhi + f);
            short8 bl = *(const short8*)(blo + f);
            acc[q] = __builtin_amdgcn_mfma_f32_16x16x32_bf16(ah[kt], bh, acc[q], 0, 0, 0);
            acc[q] = __builtin_amdgcn_mfma_f32_16x16x32_bf16(al[kt], bh, acc[q], 0, 0, 0);
            acc[q] = __builtin_amdgcn_mfma_f32_16x16x32_bf16(ah[kt], bl, acc[q], 0, 0, 0);
        }
    }

#pragma unroll
    for (int q = 0; q < 8; q++) {
        float bv = bias[col0 + q * 16 + col];
#pragma unroll
        for (int r = 0; r < 4; r++) {
            out[(size_t)(row0 + w * 16 + quad * 4 + r) * ldout + col0 + q * 16 + col]
                = acc[q][r] + bv;
        }
    }
}

// ---------------- MFMA GEMM (packed-A): A pre-packed in fragment order by gat ----------------
// No fp32 read, no conversion, no LDS, no barrier; lane-sequential 16B loads.
__global__ __launch_bounds__(256) void gemm_mfp(
    const ushort* __restrict__ ahiP, const ushort* __restrict__ aloP,
    const ushort* __restrict__ bhi, const ushort* __restrict__ blo,
    const float* __restrict__ bias, float* __restrict__ out, const int ldout)
{
    constexpr int KT = 4;
    const int t = threadIdx.x;
    const int w = t >> 6, lane = t & 63;
    const int quad = lane >> 4, col = lane & 15;
    const int row0 = blockIdx.x * 64;
    const int col0 = blockIdx.y * 128;
    const size_t abase = (size_t)blockIdx.x * PTILE;

    short8 ah[KT], al[KT];
#pragma unroll
    for (int kt = 0; kt < KT; kt++) {
        const int off = ((kt * 4 + w) * 64 + lane) * 8;
        ah[kt] = *(const short8*)(ahiP + abase + off);
        al[kt] = *(const short8*)(aloP + abase + off);
    }

    f32x4 acc[8];
#pragma unroll
    for (int q = 0; q < 8; q++) acc[q] = (f32x4){0.f, 0.f, 0.f, 0.f};

#pragma unroll
    for (int q = 0; q < 8; q++) {
#pragma unroll
        for (int kt = 0; kt < KT; kt++) {
            const int f = ((((col0 >> 4) + q) * KT + kt) * 64 + lane) * 8;
            short8 bh = *(const short8*)(bhi + f);
            short8 bl = *(const short8*)(blo + f);
            acc[q] = __builtin_amdgcn_mfma_f32_16x16x32_bf16(ah[kt], bh, acc[q], 0, 0, 0);
            acc[q] = __builtin_amdgcn_mfma_f32_16x16x32_bf16(al[kt], bh, acc[q], 0, 0, 0);
            acc[q] = __builtin_amdgcn_mfma_f32_16x16x32_bf16(ah[kt], bl, acc[q], 0, 0, 0);
        }
    }

#pragma unroll
    for (int q = 0; q < 8; q++) {
        float bv = bias[col0 + q * 16 + col];
#pragma unroll
        for (int r = 0; r < 4; r++) {
            out[(size_t)(row0 + w * 16 + quad * 4 + r) * ldout + col0 + q * 16 + col]
                = acc[q][r] + bv;
        }
    }
}

// ---------------- fused W7 GEMM + row-dot: logit2[row] = relu(x@W7+b7)·w5h ----------------
// The gs/meanpool term and b5 are CONSTANT per sequence row -> they cancel in
// the masked softmax over nodes (shift invariance). So prob only needs
// relu(la)·w5[128:], fused here into the GEMM epilogue.
__global__ __launch_bounds__(256) void gemm_w7dot(
    const float* __restrict__ x, const ushort* __restrict__ bhi,
    const ushort* __restrict__ blo, const float* __restrict__ bias,
    const float* __restrict__ w5h, float* __restrict__ logit2)
{
    constexpr int KT = 4;
    constexpr int K = 128;
    __shared__ __align__(16) ushort ahi_s[KT * 4 * 64 * 8];
    __shared__ __align__(16) ushort alo_s[KT * 4 * 64 * 8];
    const int t = threadIdx.x;
    const int w = t >> 6, lane = t & 63;
    const int quad = lane >> 4, col = lane & 15;
    const int row0 = blockIdx.x * 64;

    {
        const int r  = t >> 2;
        const int kc = (t & 3) * (K / 4);
        const int rw = r >> 4, rcol = r & 15;
        const float* xr = x + (size_t)(row0 + r) * K + kc;
#pragma unroll
        for (int k = 0; k < K / 4; k += 4) {
            const int ch = kc + k;
            const int idx = (((ch >> 5) * 4 + rw) * 64 + ((ch >> 3) & 3) * 16 + rcol) * 8
                            + (ch & 7);
            float4 v = *(const float4*)(xr + k);
            ushort h0_ = f2bf(v.x), h1_ = f2bf(v.y), h2_ = f2bf(v.z), h3_ = f2bf(v.w);
            ushort l0_ = f2bf(v.x - bf2f(h0_)), l1_ = f2bf(v.y - bf2f(h1_));
            ushort l2_ = f2bf(v.z - bf2f(h2_)), l3_ = f2bf(v.w - bf2f(h3_));
            *(uint2*)(ahi_s + idx) = make_uint2((uint)h0_ | ((uint)h1_ << 16),
                                                (uint)h2_ | ((uint)h3_ << 16));
            *(uint2*)(alo_s + idx) = make_uint2((uint)l0_ | ((uint)l1_ << 16),
                                                (uint)l2_ | ((uint)l3_ << 16));
        }
    }
    __syncthreads();

    short8 ah[KT], al[KT];
#pragma unroll
    for (int kt = 0; kt < KT; kt++) {
        const int off = ((kt * 4 + w) * 64 + lane) * 8;
        ah[kt] = *(const short8*)(ahi_s + off);
        al[kt] = *(const short8*)(alo_s + off);
    }

    f32x4 acc[8];
#pragma unroll
    for (int q = 0; q < 8; q++) acc[q] = (f32x4){0.f, 0.f, 0.f, 0.f};

#pragma unroll
    for (int q = 0; q < 8; q++) {
#pragma unroll
        for (int kt = 0; kt < KT; kt++) {
            const int f = ((q * KT + kt) * 64 + lane) * 8;
            short8 bh = *(const short8*)(bhi + f);
            short8 bl = *(const short8*)(blo + f);
            acc[q] = __builtin_amdgcn_mfma_f32_16x16x32_bf16(ah[kt], bh, acc[q], 0, 0, 0);
            acc[q] = __builtin_amdgcn_mfma_f32_16x16x32_bf16(al[kt], bh, acc[q], 0, 0, 0);
            acc[q] = __builtin_amdgcn_mfma_f32_16x16x32_bf16(ah[kt], bl, acc[q], 0, 0, 0);
        }
    }

    // epilogue: per-row dot with w5h over the 128 output channels
    float part0 = 0.f, part1 = 0.f, part2 = 0.f, part3 = 0.f;
#pragma unroll
    for (int q = 0; q < 8; q++) {
        float bv = bias[q * 16 + col];
        float wv = w5h[q * 16 + col];
        part0 += fmaxf(acc[q][0] + bv, 0.f) * wv;
        part1 += fmaxf(acc[q][1] + bv, 0.f) * wv;
        part2 += fmaxf(acc[q][2] + bv, 0.f) * wv;
        part3 += fmaxf(acc[q][3] + bv, 0.f) * wv;
    }
#pragma unroll
    for (int o = 1; o < 16; o <<= 1) {
        part0 += __shfl_xor(part0, o);
        part1 += __shfl_xor(part1, o);
        part2 += __shfl_xor(part2, o);
        part3 += __shfl_xor(part3, o);
    }
    if (col == 0) {
        const int rbase = row0 + w * 16 + quad * 4;
        logit2[rbase + 0] = part0;
        logit2[rbase + 1] = part1;
        logit2[rbase + 2] = part2;
        logit2[rbase + 3] = part3;
    }
}

// ---------------- fp32 GEMM (fallback path only) ----------------
template <int K>
__global__ __launch_bounds__(256) void gemm3(
    const float* __restrict__ x, const float* __restrict__ W,
    const float* __restrict__ b, float* __restrict__ out)
{
    __shared__ float Wsh[64 * 128];
    __shared__ float xT[64][132];
    const int t = threadIdx.x;
    const int row0 = blockIdx.x * 128;
    const int cg = t & 15;
    const int rg = t >> 4;
    float4 acc[8][2];
#pragma unroll
    for (int r = 0; r < 8; r++) {
        acc[r][0] = make_float4(0.f, 0.f, 0.f, 0.f);
        acc[r][1] = make_float4(0.f, 0.f, 0.f, 0.f);
    }
    for (int k0 = 0; k0 < K; k0 += 64) {
        for (int i = t * 4; i < 64 * 128; i += 1024)
            *(float4*)(Wsh + i) = *(const float4*)(W + (size_t)k0 * 128 + i);
        for (int i = t * 4; i < 128 * 64; i += 1024) {
            int r = i >> 6, k = i & 63;
            float4 v = *(const float4*)(x + (size_t)(row0 + r) * K + k0 + k);
            xT[k + 0][r] = v.x; xT[k + 1][r] = v.y;
            xT[k + 2][r] = v.z; xT[k + 3][r] = v.w;
        }
        __syncthreads();
#pragma unroll 2
        for (int k = 0; k < 64; k++) {
            float4 w0 = *(const float4*)(Wsh + k * 128 + cg * 8);
            float4 w1 = *(const float4*)(Wsh + k * 128 + cg * 8 + 4);
            float4 x0 = *(const float4*)(&xT[k][rg * 8]);
            float4 x1 = *(const float4*)(&xT[k][rg * 8 + 4]);
            float xv[8] = {x0.x, x0.y, x0.z, x0.w, x1.x, x1.y, x1.z, x1.w};
#pragma unroll
            for (int r = 0; r < 8; r++) {
                acc[r][0].x += xv[r] * w0.x; acc[r][0].y += xv[r] * w0.y;
                acc[r][0].z += xv[r] * w0.z; acc[r][0].w += xv[r] * w0.w;
                acc[r][1].x += xv[r] * w1.x; acc[r][1].y += xv[r] * w1.y;
                acc[r][1].z += xv[r] * w1.z; acc[r][1].w += xv[r] * w1.w;
            }
        }
        __syncthreads();
    }
    float4 bv0 = *(const float4*)(b + cg * 8);
    float4 bv1 = *(const float4*)(b + cg * 8 + 4);
#pragma unroll
    for (int r = 0; r < 8; r++) {
        float4 o0, o1;
        o0.x = acc[r][0].x + bv0.x; o0.y = acc[r][0].y + bv0.y;
        o0.z = acc[r][0].z + bv0.z; o0.w = acc[r][0].w + bv0.w;
        o1.x = acc[r][1].x + bv1.x; o1.y = acc[r][1].y + bv1.y;
        o1.z = acc[r][1].z + bv1.z; o1.w = acc[r][1].w + bv1.w;
        float* op = out + (size_t)(row0 + rg * 8 + r) * 128 + cg * 8;
        *(float4*)(op) = o0;
        *(float4*)(op + 4) = o1;
    }
}

// ---------------- fused GATv2 v5: 4 edges/wave (2 chains per 32-lane half) ----------------
// r7-proven loop (frozen). PACKED=true epilogue stores bf16 hi/lo planes in
// MFMA fragment order (same bytes as fp32; f2bf of the same register values
// the staged gemm would have converted -> bitwise-identical downstream).
template <bool PACKED>
__global__ __launch_bounds__(256) void gat_fused_k(
    const float* __restrict__ xl, const int* __restrict__ rowptr,
    const int* __restrict__ srcs, const float* __restrict__ att,
    const float* __restrict__ bias, float* __restrict__ out,
    ushort* __restrict__ outhi, ushort* __restrict__ outlo, const int do_relu)
{
    const int lane = threadIdx.x & 63;
    const int q = lane & 31;           // channel group: ch q*4..q*4+3 (q<16 head0)
    const int h = lane >> 5;           // edge slot 0/1
    const int b = blockIdx.x;
    const int g = b & 7;
    const int j = b >> 3;
    const int jq = j / 250;
    const int jj = j - jq * 250;
    const int s = g + 8 * jq;
    const int n = s * NN + jj * 4 + (threadIdx.x >> 6);

    const float4 a4 = *(const float4*)(att + q * 4);
    const float4 xd = *(const float4*)(xl + (size_t)n * 128 + q * 4);
    const int i0 = rowptr[n], i1 = rowptr[n + 1];

    float mA = -1e30f, dA = 0.f, axA = 0.f, ayA = 0.f, azA = 0.f, awA = 0.f;
    float mB = -1e30f, dB = 0.f, axB = 0.f, ayB = 0.f, azB = 0.f, awB = 0.f;

    int iA = i0 + h, iB = i0 + h + 2;
    int svA = (iA < i1) ? srcs[iA] : 0;
    int svB = (iB < i1) ? srcs[iB] : 0;
    float4 xsA = *(const float4*)(xl + (size_t)svA * 128 + q * 4);
    float4 xsB = *(const float4*)(xl + (size_t)svB * 128 + q * 4);

    for (int base = i0; base < i1; base += 4) {
        const bool vA = (iA < i1), vB = (iB < i1);
        const int svA2 = (iA + 4 < i1) ? srcs[iA + 4] : 0;     // prefetch next iter
        const int svB2 = (iB + 4 < i1) ? srcs[iB + 4] : 0;
        const float4 xA2 = *(const float4*)(xl + (size_t)svA2 * 128 + q * 4);
        const float4 xB2 = *(const float4*)(xl + (size_t)svB2 * 128 + q * 4);

        float uA0 = xsA.x + xd.x, uA1 = xsA.y + xd.y;
        float uA2 = xsA.z + xd.z, uA3 = xsA.w + xd.w;
        float uB0 = xsB.x + xd.x, uB1 = xsB.y + xd.y;
        float uB2 = xsB.z + xd.z, uB3 = xsB.w + xd.w;
        float pA, pB;
        pA  = a4.x * fmaxf(uA0, 0.2f * uA0);
        pA += a4.y * fmaxf(uA1, 0.2f * uA1);
        pA += a4.z * fmaxf(uA2, 0.2f * uA2);
        pA += a4.w * fmaxf(uA3, 0.2f * uA3);
        pB  = a4.x * fmaxf(uB0, 0.2f * uB0);
        pB += a4.y * fmaxf(uB1, 0.2f * uB1);
        pB += a4.z * fmaxf(uB2, 0.2f * uB2);
        pB += a4.w * fmaxf(uB3, 0.2f * uB3);
        // head logit: sum within the 16-lane group; two independent chains
        pA += __shfl_xor(pA, 1);   pB += __shfl_xor(pB, 1);
        pA += __shfl_xor(pA, 2);   pB += __shfl_xor(pB, 2);
        pA += __shfl_xor(pA, 4);   pB += __shfl_xor(pB, 4);
        pA += __shfl_xor(pA, 8);   pB += __shfl_xor(pB, 8);

        float mnA = fmaxf(mA, vA ? pA : -1e30f);
        float mnB = fmaxf(mB, vB ? pB : -1e30f);
        float scA = __expf(mA - mnA), scB = __expf(mB - mnB);
        float wA = vA ? __expf(pA - mnA) : 0.f;
        float wB = vB ? __expf(pB - mnB) : 0.f;
        dA  = dA  * scA + wA;          dB  = dB  * scB + wB;
        axA = axA * scA + wA * xsA.x;  axB = axB * scB + wB * xsB.x;
        ayA = ayA * scA + wA * xsA.y;  ayB = ayB * scB + wB * xsB.y;
        azA = azA * scA + wA * xsA.z;  azB = azB * scB + wB * xsB.z;
        awA = awA * scA + wA * xsA.w;  awB = awB * scB + wB * xsB.w;
        mA = mnA; mB = mnB;
        xsA = xA2; xsB = xB2;
        iA += 4; iB += 4;
    }

    // merge chain B into chain A (within lane)
    float m1 = fmaxf(mA, mB);
    float sA = __expf(mA - m1), sB = __expf(mB - m1);
    float d  = dA * sA + dB * sB;
    float ax = axA * sA + axB * sB;
    float ay = ayA * sA + ayB * sB;
    float az = azA * sA + azB * sB;
    float aw = awA * sA + awB * sB;
    float m  = m1;

    // merge slot states (lanes l and l^32 hold the same channels)
    float m2 = __shfl_xor(m, 32);
    float d2 = __shfl_xor(d, 32);
    float bx = __shfl_xor(ax, 32);
    float by = __shfl_xor(ay, 32);
    float bz = __shfl_xor(az, 32);
    float bw = __shfl_xor(aw, 32);
    float mm = fmaxf(m, m2);
    float s1 = __expf(m - mm), s2 = __expf(m2 - mm);
    float den = d * s1 + d2 * s2;
    float inv = 1.f / den;
    float4 bv = *(const float4*)(bias + q * 4);
    float ox = (ax * s1 + bx * s2) * inv + bv.x;
    float oy = (ay * s1 + by * s2) * inv + bv.y;
    float oz = (az * s1 + bz * s2) * inv + bv.z;
    float ow = (aw * s1 + bw * s2) * inv + bv.w;
    if (do_relu) {
        ox = fmaxf(ox, 0.f); oy = fmaxf(oy, 0.f);
        oz = fmaxf(oz, 0.f); ow = fmaxf(ow, 0.f);
    }
    if (lane < 32) {
        if (PACKED) {
            // fragment-order packed store (channels q*4..q*4+3 share one 8B slot)
            const int tile = n >> 6, r = n & 63;
            const int rw = r >> 4, rcol = r & 15;
            const size_t idx = (size_t)tile * PTILE +
                (size_t)((((q >> 3) * 4 + rw) * 64 + ((q >> 1) & 3) * 16 + rcol) * 8
                         + (q & 1) * 4);
            ushort h0 = f2bf(ox), h1 = f2bf(oy), h2 = f2bf(oz), h3 = f2bf(ow);
            ushort l0 = f2bf(ox - bf2f(h0)), l1 = f2bf(oy - bf2f(h1));
            ushort l2 = f2bf(oz - bf2f(h2)), l3 = f2bf(ow - bf2f(h3));
            *(uint2*)(outhi + idx) = make_uint2((uint)h0 | ((uint)h1 << 16),
                                                (uint)h2 | ((uint)h3 << 16));
            *(uint2*)(outlo + idx) = make_uint2((uint)l0 | ((uint)l1 << 16),
                                                (uint)l2 | ((uint)l3 << 16));
        } else {
            *(float4*)(out + (size_t)n * 128 + q * 4) = make_float4(ox, oy, oz, ow);
        }
    }
}

// ---------------- LSTM weight packing (fallback path) ----------------
__global__ void build_wq_k(const float* __restrict__ Wih, const float* __restrict__ Whh,
                           float4* __restrict__ WQa, float4* __restrict__ WQb) {
    int id = blockIdx.x * 256 + threadIdx.x;
    if (id < 64 * 256) {
        int kp = id >> 8, t = id & 255;
        int j1 = t, j2 = t + 256;
        WQa[id] = make_float4(Wih[(size_t)j1 * 128 + 2 * kp], Whh[(size_t)j1 * 128 + 2 * kp],
                              Wih[(size_t)j1 * 128 + 2 * kp + 1], Whh[(size_t)j1 * 128 + 2 * kp + 1]);
        WQb[id] = make_float4(Wih[(size_t)j2 * 128 + 2 * kp], Whh[(size_t)j2 * 128 + 2 * kp],
                              Wih[(size_t)j2 * 128 + 2 * kp + 1], Whh[(size_t)j2 * 128 + 2 * kp + 1]);
    }
}

// ---- fallback LSTM (round-3, small-ws only) ----
#define LSTM_GROUP(buf, gbase)                                                     \
    _Pragma("unroll")                                                              \
    for (int i_ = 0; i_ < 4; i_++) {                                               \
        const int kp_ = (gbase) * 4 + i_;                                          \
        const float4 qa_ = buf[i_];                                                \
        const float4 qb_ = buf[4 + i_];                                            \
        _Pragma("unroll")                                                          \
        for (int n_ = 0; n_ < 4; n_++) {                                           \
            const float sx0_ = rdlane(xr[n_].x, kp_);                              \
            const float sh0_ = rdlane(hr[n_].x, kp_);                              \
            const float sx1_ = rdlane(xr[n_].y, kp_);                              \
            const float sh1_ = rdlane(hr[n_].y, kp_);                              \
            acc1[n_] += sx0_ * qa_.x + sh0_ * qa_.y + sx1_ * qa_.z + sh1_ * qa_.w; \
            acc2[n_] += sx0_ * qb_.x + sh0_ * qb_.y + sx1_ * qb_.z + sh1_ * qb_.w; \
        }                                                                          \
    }

__global__ __launch_bounds__(256, 1) void lstm_k(
    float* __restrict__ mu, const float4* __restrict__ WQa, const float4* __restrict__ WQb,
    const float* __restrict__ bih, const float* __restrict__ bhh,
    const float* __restrict__ h0, const float* __restrict__ c0,
    float* __restrict__ hT, float* __restrict__ cT)
{
    const int t = threadIdx.x, lane = t & 63;
    const int n0 = blockIdx.x * 4;
    __shared__ float hsh[4][128];
    __shared__ float gsh[4][512];
    const float b1 = bih[t] + bhh[t];
    const float b2 = bih[t + 256] + bhh[t + 256];
    float creg[2];
#pragma unroll
    for (int q = 0; q < 2; q++) {
        int id = t + 256 * q;
        creg[q] = c0[(size_t)(n0 + (id >> 7)) * 128 + (id & 127)];
    }
    for (int i = t; i < 512; i += 256)
        hsh[i >> 7][i & 127] = h0[(size_t)(n0 + (i >> 7)) * 128 + (i & 127)];

    const float4* pA = WQa + t;
    const float4* pB = WQb + t;

    float2 xr[4], xnx[4];
#pragma unroll
    for (int n = 0; n < 4; n++)
        xr[n] = *(const float2*)(mu + (size_t)n0 * 128 + n * 128 + lane * 2);
    __syncthreads();

    for (int s = 0; s < SQ; s++) {
        float* xrow = mu + ((size_t)s * NN + n0) * 128;
        float2 hr[4];
#pragma unroll
        for (int n = 0; n < 4; n++) hr[n] = *(const float2*)(&hsh[n][lane * 2]);

        float4 bufA[8], bufB[8];
#pragma unroll
        for (int i = 0; i < 4; i++) { bufA[i] = pA[i * 256]; bufA[4 + i] = pB[i * 256]; }

        if (s + 1 < SQ) {
            const float* xrow2 = mu + ((size_t)(s + 1) * NN + n0) * 128;
#pragma unroll
            for (int n = 0; n < 4; n++) xnx[n] = *(const float2*)(xrow2 + n * 128 + lane * 2);
        }

        float acc1[4], acc2[4];
#pragma unroll
        for (int n = 0; n < 4; n++) { acc1[n] = b1; acc2[n] = b2; }

        for (int g = 0; g < 16; g += 2) {
#pragma unroll
            for (int i = 0; i < 4; i++) {
                bufB[i]     = pA[((g + 1) * 4 + i) * 256];
                bufB[4 + i] = pB[((g + 1) * 4 + i) * 256];
            }
            LSTM_GROUP(bufA, g)
            if (g < 14) {
#pragma unroll
                for (int i = 0; i < 4; i++) {
                    bufA[i]     = pA[((g + 2) * 4 + i) * 256];
                    bufA[4 + i] = pB[((g + 2) * 4 + i) * 256];
                }
            }
            LSTM_GROUP(bufB, g + 1)
        }

#pragma unroll
        for (int n = 0; n < 4; n++) { gsh[n][t] = acc1[n]; gsh[n][t + 256] = acc2[n]; }
        __syncthreads();
#pragma unroll
        for (int q = 0; q < 2; q++) {
            int id = t + 256 * q;
            int n = id >> 7, e = id & 127;
            float iv = gsh[n][e], fv = gsh[n][128 + e];
            float gv = gsh[n][256 + e], ov = gsh[n][384 + e];
            float c = sigm(fv) * creg[q] + sigm(iv) * tanh_f(gv);
            float h = sigm(ov) * tanh_f(c);
            creg[q] = c;
            hsh[n][e] = h;
            xrow[n * 128 + e] = h;
            if (s == SQ - 1) {
                hT[(size_t)(n0 + n) * 128 + e] = h;
                cT[(size_t)(n0 + n) * 128 + e] = c;
            }
        }
#pragma unroll
        for (int n = 0; n < 4; n++) xr[n] = xnx[n];
        __syncthreads();
    }
}

// ---------------- MFMA LSTM v8 (big-ws path) — PROVEN BEST (87-90us) ----------------
// r13 post-mortem: fragment-order packed mu store cost +7us (scattered 2B
// stores); fp32 coalesced row store + staged head is the better split.
__global__ __launch_bounds__(512, 2) void lstm8_k(
    float* __restrict__ mu, const float* __restrict__ xC,
    const ushort* __restrict__ Bfrag,
    const float* __restrict__ h0, const float* __restrict__ c0,
    float* __restrict__ hT, float* __restrict__ cT)
{
    const int t = threadIdx.x;
    const int w = t >> 6, lane = t & 63;
    const int quad = lane >> 4, col = lane & 15;
    const int n0 = blockIdx.x * 4;                // 250 * 4 = 1000 exactly
    const int enode = t >> 7;                     // epilogue node 0..3
    const int ech   = t & 127;                    // epilogue channel 0..127

    __shared__ __align__(16) ushort hbuf[2][2][16 * 136];   // [pingpong][hi/lo]
    __shared__ float gsh[4][512];                           // gate preacts (h@Whh)

    // B fragments: wave w owns gate tiles {g4*8 + w}, g4 = i,f,g,o group
    short8 bf[4][4];
#pragma unroll
    for (int g4 = 0; g4 < 4; g4++)
#pragma unroll
        for (int kt = 0; kt < 4; kt++) {
            int tile = g4 * 8 + w;
            bf[g4][kt] = *(const short8*)(Bfrag + (((tile * 4 + kt) * 64 + lane) << 3));
        }

    // init hbuf: rows 0..3 = h0, rows 4..15 = 0 (stay 0 forever); both buffers
    for (int i = t; i < 2048; i += 512) {
        int node = i >> 7, ee = i & 127;
        float v = (node < 4) ? h0[(size_t)(n0 + node) * 128 + ee] : 0.f;
        ushort hh = f2bf(v), hl = f2bf(v - bf2f(hh));
        hbuf[0][0][node * 136 + ee] = hh; hbuf[0][1][node * 136 + ee] = hl;
        hbuf[1][0][node * 136 + ee] = hh; hbuf[1][1][node * 136 + ee] = hl;
    }
    float cst = c0[(size_t)(n0 + enode) * 128 + ech];

    // preload step-0 xC gate preacts for this thread's (node, channel)
    float xcr[4], xcn[4];
#pragma unroll
    for (int g4 = 0; g4 < 4; g4++)
        xcr[g4] = xC[((size_t)(n0 + enode)) * 512 + g4 * 128 + ech];
    __syncthreads();

    int p = 0;
    for (int s = 0; s < SQ; s++) {
        // 1. issue next step's xC loads — consumed NEXT iteration
        if (s + 1 < SQ) {
            const float* xn = xC + ((size_t)(s + 1) * NN + n0 + enode) * 512;
#pragma unroll
            for (int g4 = 0; g4 < 4; g4++)
                xcn[g4] = xn[g4 * 128 + ech];
        }

        // 2. A fragments from current h buffer (row = col lane; rows>=4 are 0)
        short8 ahi[4], alo[4];
#pragma unroll
        for (int kt = 0; kt < 4; kt++) {
            ahi[kt] = *(const short8*)(&hbuf[p][0][col * 136 + kt * 32 + quad * 8]);
            alo[kt] = *(const short8*)(&hbuf[p][1][col * 136 + kt * 32 + quad * 8]);
        }

        // 3. MFMA: 32 issues, 4 independent acc chains
        f32x4 acc[4];
#pragma unroll
        for (int g4 = 0; g4 < 4; g4++) acc[g4] = (f32x4){0.f, 0.f, 0.f, 0.f};
#pragma unroll
        for (int kt = 0; kt < 4; kt++) {
#pragma unroll
            for (int g4 = 0; g4 < 4; g4++)
                acc[g4] = __builtin_amdgcn_mfma_f32_16x16x32_bf16(ahi[kt], bf[g4][kt], acc[g4], 0, 0, 0);
#pragma unroll
            for (int g4 = 0; g4 < 4; g4++)
                acc[g4] = __builtin_amdgcn_mfma_f32_16x16x32_bf16(alo[kt], bf[g4][kt], acc[g4], 0, 0, 0);
        }

        // 4. scatter valid rows (nodes 0..3 live in quad-0 lanes) to gsh
        if (quad == 0) {
#pragma unroll
            for (int g4 = 0; g4 < 4; g4++)
#pragma unroll
                for (int r = 0; r < 4; r++)
                    gsh[r][(g4 * 8 + w) * 16 + col] = acc[g4][r];
        }
        __syncthreads();

        // 5. dense epilogue: each thread one (node, channel)
        {
            float iv = gsh[enode][0 * 128 + ech] + xcr[0];
            float fv = gsh[enode][1 * 128 + ech] + xcr[1];
            float gv = gsh[enode][2 * 128 + ech] + xcr[2];
            float ov = gsh[enode][3 * 128 + ech] + xcr[3];
            float c = sigm(fv) * cst + sigm(iv) * tanh2(gv);
            float h = sigm(ov) * tanh2(c);
            cst = c;
            const int pn = p ^ 1;
            ushort hh = f2bf(h);
            hbuf[pn][0][enode * 136 + ech] = hh;
            hbuf[pn][1][enode * 136 + ech] = f2bf(h - bf2f(hh));
            mu[((size_t)s * NN + n0 + enode) * 128 + ech] = h;   // contiguous per block
            if (s == SQ - 1) {
                hT[(size_t)(n0 + enode) * 128 + ech] = h;
                cT[(size_t)(n0 + enode) * 128 + ech] = c;
            }
            p = pn;
        }
#pragma unroll
        for (int g4 = 0; g4 < 4; g4++) xcr[g4] = xcn[g4];
        __syncthreads();
    }
}

// ---------------- head: logit2[row] (fallback path; gs/b5 cancel in softmax) ----------------
__global__ __launch_bounds__(256) void rowdot_k(
    const float* __restrict__ la, const float* __restrict__ w5,
    float* __restrict__ out)
{
    const int lane = threadIdx.x & 63;
    const int row = blockIdx.x * 4 + (threadIdx.x >> 6);
    float2 v = *(const float2*)(la + (size_t)row * 128 + lane * 2);
    float2 w = *(const float2*)(w5 + 128 + lane * 2);
    float x = fmaxf(v.x, 0.f) * w.x + fmaxf(v.y, 0.f) * w.y;
#pragma unroll
    for (int o = 32; o; o >>= 1) x += __shfl_down(x, o);
    if (lane == 0) out[row] = x;
}

// ---------------- masked softmax per sequence step ----------------
__device__ __forceinline__ bool reach_at(const void* reach, int mode, int idx) {
    if (mode == 0) return ((const int*)reach)[idx] != 0;
    if (mode == 1) return ((const unsigned char*)reach)[idx] != 0;
    return ((const float*)reach)[idx] != 0.f;
}
__global__ __launch_bounds__(256) void softmax_k(
    const float* __restrict__ lg, const void* __restrict__ reach,
    const int* __restrict__ mode, float* __restrict__ prob)
{
    const int s = blockIdx.x, t = threadIdx.x;
    const int m = *mode;
    __shared__ float red[256];
    float mx = -1e30f;
    for (int i = t; i < NN; i += 256) {
        int idx = s * NN + i;
        if (reach_at(reach, m, idx)) mx = fmaxf(mx, lg[idx]);
    }
    red[t] = mx;
    __syncthreads();
    for (int o = 128; o; o >>= 1) {
        if (t < o) red[t] = fmaxf(red[t], red[t + o]);
        __syncthreads();
    }
    mx = red[0];
    __syncthreads();
    float sum = 0.f;
    for (int i = t; i < NN; i += 256) {
        int idx = s * NN + i;
        float v = reach_at(reach, m, idx) ? __expf(lg[idx] - mx) : 0.f;
        prob[idx] = v;
        sum += v;
    }
    red[t] = sum;
    __syncthreads();
    for (int o = 128; o; o >>= 1) {
        if (t < o) red[t] += red[t + o];
        __syncthreads();
    }
    float inv = 1.f / red[0];
    for (int i = t; i < NN; i += 256) prob[s * NN + i] *= inv;
}

// ---------------- driver ----------------
extern "C" void kernel_launch(void* const* d_in, const int* in_sizes, int n_in,
                              void* d_out, int out_size, void* d_ws, size_t ws_size,
                              hipStream_t stream) {
    const float* nfm   = (const float*)d_in[0];
    const int*   ei    = (const int*)d_in[1];
    const void*  reach = d_in[2];
    const float* h0    = (const float*)d_in[3];
    const float* c0    = (const float*)d_in[4];
    const float* W1    = (const float*)d_in[5];
    const float* b1    = (const float*)d_in[6];
    const float* att1  = (const float*)d_in[7];
    const float* bias1 = (const float*)d_in[8];
    const float* Wl    = (const float*)d_in[9];
    const float* bl    = (const float*)d_in[10];
    const float* attl  = (const float*)d_in[11];
    const float* biasl = (const float*)d_in[12];
    const float* Wih   = (const float*)d_in[13];
    const float* Whh   = (const float*)d_in[14];
    const float* bih   = (const float*)d_in[15];
    const float* bhh   = (const float*)d_in[16];
    const float* W6    = (const float*)d_in[17];
    const float* b6    = (const float*)d_in[18];
    const float* W7    = (const float*)d_in[19];
    const float* b7    = (const float*)d_in[20];
    const float* w5    = (const float*)d_in[21];
    const float* b5    = (const float*)d_in[22];
    (void)W6; (void)b6; (void)b5;   // gs term and b5 cancel in the node softmax

    char* ws = (char*)d_ws;
    const bool bigws = (ws_size >= WS2_NEED);

    float*  xA     = (float*)(ws + WS_XA);
    ushort* phi    = (ushort*)(ws + WS_PHI);
    ushort* plo    = (ushort*)(ws + WS_PLO);
    float*  xB     = (float*)(ws + WS_XB);
    int*    rowptr = (int*)(ws + WS_ROWPTR);
    int*    cursor = (int*)(ws + WS_CURSOR);
    int*    srcs   = (int*)(ws + WS_SRCS);
    int*    incl   = (int*)(ws + WS_INCL);
    int*    bsum   = (int*)(ws + WS_BSUM);
    int*    modep  = bigws ? (int*)(ws + WS2_MODE)     : (int*)(ws + WS_MODE);
    float*  logit2 = bigws ? (float*)(ws + WS2_LOGIT2) : (float*)(ws + WS_LOGIT2);
    // big-ws extras
    float*  xC     = (float*)(ws + WS2_XC);
    ushort* Bfrag  = (ushort*)(ws + WS2_BFRAG);
    ushort* ghi    = (ushort*)(ws + WS2_GHI);
    ushort* glo    = (ushort*)(ws + WS2_GLO);
    float*  b512   = (float*)(ws + WS2_B512);
    // fallback extras
    float4* WQa    = (float4*)(ws + WS_WQA);
    float4* WQb    = (float4*)(ws + WS_WQB);

    float* prob = (float*)d_out;
    float* hT   = (float*)d_out + 64000;
    float* cT   = (float*)d_out + 192000;

    // setup
    detect_mode_k<<<1, 1024, 0, stream>>>((const unsigned char*)reach, modep);
    zero_ints_k<<<250, 256, 0, stream>>>(cursor, NT);
    hist_k<<<2250, 256, 0, stream>>>(ei, cursor);
    scan1_k<<<250, 256, 0, stream>>>(cursor, incl, bsum);
    scan3_k<<<250, 256, 0, stream>>>(incl, bsum, rowptr, cursor);
    fill_k<<<2250, 256, 0, stream>>>(ei, cursor, srcs);
    if (bigws) {
        build_all_k<<<866, 256, 0, stream>>>(Whh, bih, bhh, W1, Wl, Wih, W7,
                                             Bfrag, b512, ghi, glo);
    } else {
        build_wq_k<<<64, 256, 0, stream>>>(Wih, Whh, WQa, WQb);
    }

    // 5 GATv2 layers
    for (int l = 0; l < 5; l++) {
        const float* att  = (l == 0) ? att1  : attl  + (l - 1) * 128;
        const float* bias = (l == 0) ? bias1 : biasl + (l - 1) * 128;
        if (bigws) {
            if (l == 0)
                gemm_mf<2><<<dim3(1000, 1), 256, 0, stream>>>(nfm, ghi + G_W1, glo + G_W1, b1, xB, 128);
            else
                gemm_mfp<<<dim3(1000, 1), 256, 0, stream>>>(phi, plo,
                                                            ghi + G_WL + (l - 1) * 16384,
                                                            glo + G_WL + (l - 1) * 16384,
                                                            bl + (l - 1) * 128, xB, 128);
            // gat writes packed bf16 hi/lo planes (fragment order) for next consumer
            gat_fused_k<true><<<16000, 256, 0, stream>>>(xB, rowptr, srcs, att, bias,
                                                         nullptr, phi, plo, (l < 4) ? 1 : 0);
        } else {
            if (l == 0)
                gemm3<64><<<500, 256, 0, stream>>>(nfm, W1, b1, xB);
            else
                gemm3<128><<<500, 256, 0, stream>>>(xA, Wl + (size_t)(l - 1) * 128 * 128,
                                                    bl + (l - 1) * 128, xB);
            gat_fused_k<false><<<16000, 256, 0, stream>>>(xB, rowptr, srcs, att, bias,
                                                          xA, nullptr, nullptr, (l < 4) ? 1 : 0);
        }
    }

    // LSTM
    if (bigws) {
        // xC = mu @ Wih^T + (bih+bhh); A read directly from packed planes (gat L5)
        gemm_mfp<<<dim3(1000, 4), 256, 0, stream>>>(phi, plo, ghi + G_PROJ, glo + G_PROJ,
                                                    b512, xC, 512);
        // lstm8 overwrites phi/plo region (now dead) with fp32 mu rows (coalesced)
        lstm8_k<<<250, 512, 0, stream>>>(xA, xC, Bfrag, h0, c0, hT, cT);
    } else {
        lstm_k<<<250, 256, 0, stream>>>(xA, WQa, WQb, bih, bhh, h0, c0, hT, cT);
    }

    // head: logits (gs/meanpool term + b5 cancel in the per-row softmax)
    if (bigws) {
        gemm_w7dot<<<1000, 256, 0, stream>>>(xA, ghi + G_W7, glo + G_W7, b7, w5 + 128, logit2);
    } else {
        gemm3<128><<<500, 256, 0, stream>>>(xA, W7, b7, xB);
        rowdot_k<<<16000, 256, 0, stream>>>(xB, w5, logit2);
    }
    softmax_k<<<64, 256, 0, stream>>>(logit2, reach, modep, prob);
}